// Round 1
// baseline (3998.224 us; speedup 1.0000x reference)
//
#include <hip/hip_runtime.h>
#include <cstdint>

// ---------------------------------------------------------------------------
// DGCNN + STFT-KAN pipeline, fp32 correctness-first implementation.
// B=32 graphs x N=1024 points, K=20 NN, edge MLP 6->64(BN,ReLU)->128, max over K,
// STFT-KAN1 128->1024 (GEMM [32768,2912]x[2912,1024], trig A on the fly),
// global max+mean pool fused into GEMM epilogue, STFT-KAN2 2048->7.
// ---------------------------------------------------------------------------

// ---------------- kNN: one block per point ----------------
__global__ __launch_bounds__(256) void knn_kernel(const float* __restrict__ pos,
                                                  int* __restrict__ nbr) {
  __shared__ float px[1024], py[1024], pz[1024], sq[1024], d2[1024];
  __shared__ float wmin[4];
  __shared__ int warg[4];
  int bid = blockIdx.x;                // global point id
  int b = bid >> 10, n = bid & 1023;
  int tid = threadIdx.x;
  const float* pg = pos + (size_t)b * 3072;
  for (int m = 0; m < 4; ++m) {
    int j = tid + 256 * m;
    float x = pg[3 * j], y = pg[3 * j + 1], z = pg[3 * j + 2];
    px[j] = x; py[j] = y; pz[j] = z; sq[j] = x * x + y * y + z * z;
  }
  __syncthreads();
  float xi = px[n], yi = py[n], zi = pz[n], si = sq[n];
  for (int m = 0; m < 4; ++m) {
    int j = tid + 256 * m;
    float d = si + sq[j] - 2.0f * (xi * px[j] + yi * py[j] + zi * pz[j]);
    if (j == n) d += 1e10f;
    d2[j] = d;
  }
  __syncthreads();
  for (int kk = 0; kk < 20; ++kk) {
    float bv = 1e30f; int bi_ = 0x7fffffff;
    for (int m = 0; m < 4; ++m) {
      int j = tid + 256 * m;
      float d = d2[j];
      if (d < bv || (d == bv && j < bi_)) { bv = d; bi_ = j; }
    }
    for (int off = 32; off >= 1; off >>= 1) {
      float ov = __shfl_xor(bv, off);
      int   oi = __shfl_xor(bi_, off);
      if (ov < bv || (ov == bv && oi < bi_)) { bv = ov; bi_ = oi; }
    }
    if ((tid & 63) == 0) { wmin[tid >> 6] = bv; warg[tid >> 6] = bi_; }
    __syncthreads();
    if (tid == 0) {
      for (int w = 1; w < 4; ++w)
        if (wmin[w] < bv || (wmin[w] == bv && warg[w] < bi_)) { bv = wmin[w]; bi_ = warg[w]; }
      nbr[bid * 20 + kk] = b * 1024 + bi_;
      d2[bi_] = 1e30f;
    }
    __syncthreads();
  }
}

// ---------------- edge MLP layer1 stats (sum, sumsq per channel) ----------------
__global__ __launch_bounds__(256) void edge_stats_kernel(
    const float* __restrict__ pos, const int* __restrict__ nbr,
    const float* __restrict__ W1, const float* __restrict__ b1v,
    float* __restrict__ psum, float* __restrict__ psq) {
  __shared__ float els[256][6];
  __shared__ float w1s[384];
  __shared__ float b1s[64];
  __shared__ float red[8][64];
  int tid = threadIdx.x, bid = blockIdx.x;
  for (int f = tid; f < 384; f += 256) w1s[f] = W1[f];
  if (tid < 64) b1s[tid] = b1v[tid];
  int c = tid & 63, grp = tid >> 6;
  float s = 0.f, s2 = 0.f;
  for (int ch = 0; ch < 5; ++ch) {
    int E = bid * 1280 + ch * 256 + tid;
    int p = E / 20;
    int j = nbr[E];
    float pix = pos[3 * p], piy = pos[3 * p + 1], piz = pos[3 * p + 2];
    float e3 = pos[3 * j] - pix, e4 = pos[3 * j + 1] - piy, e5 = pos[3 * j + 2] - piz;
    __syncthreads();   // protect els from previous chunk's readers (also covers w1s load)
    els[tid][0] = pix; els[tid][1] = piy; els[tid][2] = piz;
    els[tid][3] = e3;  els[tid][4] = e4;  els[tid][5] = e5;
    __syncthreads();
    for (int m = 0; m < 64; ++m) {
      int e = grp * 64 + m;
      float h = b1s[c];
#pragma unroll
      for (int d = 0; d < 6; ++d) h += els[e][d] * w1s[d * 64 + c];
      s += h; s2 += h * h;
    }
  }
  red[grp][c] = s;
  __syncthreads();
  // second half (sumsq) reuses red after first write is consumed? keep both resident:
  // red is [8][64]: rows 0..3 = sums, 4..7 = sumsqs
  red[4 + grp][c] = s2;
  __syncthreads();
  if (tid < 64) {
    float S = red[0][tid] + red[1][tid] + red[2][tid] + red[3][tid];
    float Q = red[4][tid] + red[5][tid] + red[6][tid] + red[7][tid];
    psum[bid * 64 + tid] = S;
    psq[bid * 64 + tid] = Q;
  }
}

__global__ void bn_finalize_kernel(const float* __restrict__ psum, const float* __restrict__ psq,
                                   const float* __restrict__ gamma, const float* __restrict__ beta,
                                   float* __restrict__ bns, float* __restrict__ bnh) {
  int c = threadIdx.x;   // 64 threads
  float s = 0.f, q = 0.f;
  for (int b = 0; b < 512; ++b) { s += psum[b * 64 + c]; q += psq[b * 64 + c]; }
  const float inv = 1.0f / 655360.0f;
  float mu = s * inv;
  float var = q * inv - mu * mu;
  float sc = gamma[c] * rsqrtf(var + 1e-5f);
  bns[c] = sc;
  bnh[c] = beta[c] - mu * sc;
}

// ---------------- edge MLP full + max over K -> x1 [32768,128] ----------------
// 4 points per block; H = relu(bn(e@W1+b1)) staged [80][64] in LDS; W2 in LDS.
__global__ __launch_bounds__(256) void edge_mlp_kernel(
    const float* __restrict__ pos, const int* __restrict__ nbr,
    const float* __restrict__ W1, const float* __restrict__ b1v,
    const float* __restrict__ bns, const float* __restrict__ bnh,
    const float* __restrict__ W2, const float* __restrict__ b2v,
    float* __restrict__ x1) {
  __shared__ float Hl[80][65];      // 20.8 KB, pad 65 -> conflict-free column writes
  __shared__ float w2s[64][128];    // 32 KB
  __shared__ float w1s[384];
  __shared__ float b1s[64], scs[64], shs[64];
  int tid = threadIdx.x, bid = blockIdx.x;
  for (int f = tid; f < 8192; f += 256) ((float*)w2s)[f] = W2[f];
  for (int f = tid; f < 384; f += 256) w1s[f] = W1[f];
  if (tid < 64) { b1s[tid] = b1v[tid]; scs[tid] = bns[tid]; shs[tid] = bnh[tid]; }
  int d = tid & 63;
  __syncthreads();
  for (int m = 0; m < 20; ++m) {
    int flat = tid + 256 * m;
    int row = flat >> 6;            // 0..79  (uniform per wave)
    int j = nbr[bid * 80 + row];
    int P = bid * 4 + (row / 20);
    float pix = pos[3 * P], piy = pos[3 * P + 1], piz = pos[3 * P + 2];
    float e3 = pos[3 * j] - pix, e4 = pos[3 * j + 1] - piy, e5 = pos[3 * j + 2] - piz;
    float h = b1s[d];
    h += pix * w1s[d] + piy * w1s[64 + d] + piz * w1s[128 + d]
       + e3 * w1s[192 + d] + e4 * w1s[256 + d] + e5 * w1s[320 + d];
    h = scs[d] * h + shs[d];
    Hl[row][d] = fmaxf(h, 0.f);
  }
  __syncthreads();
  int p = tid >> 6;                 // point in block (0..3)
  int khalf = (tid >> 5) & 1;       // handles k-blocks {2*khalf, 2*khalf+1}
  int cgrp = tid & 31;              // 4 output cols per thread
  float best[4] = {-1e30f, -1e30f, -1e30f, -1e30f};
  for (int kb = khalf * 2; kb < khalf * 2 + 2; ++kb) {
    float acc[5][4] = {};
    for (int dd = 0; dd < 64; ++dd) {
      float4 wv = *(const float4*)(&w2s[dd][cgrp * 4]);
#pragma unroll
      for (int k5 = 0; k5 < 5; ++k5) {
        float hv = Hl[p * 20 + kb * 5 + k5][dd];
        acc[k5][0] += hv * wv.x; acc[k5][1] += hv * wv.y;
        acc[k5][2] += hv * wv.z; acc[k5][3] += hv * wv.w;
      }
    }
#pragma unroll
    for (int k5 = 0; k5 < 5; ++k5)
#pragma unroll
      for (int q = 0; q < 4; ++q) best[q] = fmaxf(best[q], acc[k5][q]);
  }
#pragma unroll
  for (int q = 0; q < 4; ++q) best[q] = fmaxf(best[q], __shfl_xor(best[q], 32));
  if (khalf == 0) {
    float4 o;
    o.x = best[0] + b2v[cgrp * 4 + 0];
    o.y = best[1] + b2v[cgrp * 4 + 1];
    o.z = best[2] + b2v[cgrp * 4 + 2];
    o.w = best[3] + b2v[cgrp * 4 + 3];
    *(float4*)(&x1[(bid * 4 + p) * 128 + cgrp * 4]) = o;
  }
}

// ---------------- KAN1 tables: j -> (input dim, window*k, phase) ----------------
__global__ void kan1_tables_kernel(int* __restrict__ dimt, float* __restrict__ wkt,
                                   float* __restrict__ pht) {
  int j = blockIdx.x * 256 + threadIdx.x;
  if (j >= 2912) return;
  int t = j / 1456, r = j % 1456;
  int n = r / 364, r2 = r % 364;
  int w = r2 / 7, g = r2 % 7;
  dimt[j] = n * 20 + w;
  float bart = 1.0f - fabsf(2.0f * (float)w / 52.0f - 1.0f);
  wkt[j] = bart * (float)(g + 1);
  pht[j] = t ? 1.57079632679489662f : 0.0f;  // sin(x) = cos(x - pi/2)
}

// ---------------- c1 [2,1024,4,52,7] -> Ct [2912,1024] ----------------
__global__ void c1_transpose_kernel(const float* __restrict__ c1, float* __restrict__ Ct) {
  int L = blockIdx.x * 256 + threadIdx.x;
  if (L >= 2912 * 1024) return;
  int j = L >> 10, o = L & 1023;
  int t = j / 1456, r = j % 1456;
  int n = r / 364, r2 = r % 364;
  int w = r2 / 7, g = r2 % 7;
  Ct[L] = c1[(((t * 1024 + o) * 4 + n) * 52 + w) * 7 + g];
}

// ---------------- KAN1 GEMM [32768,2912]x[2912,1024], A = trig on the fly ----------------
// BM=64 BN=128 BK=32, 256 thr, 4x8 micro-tile; fused max/sum pooling epilogue.
__global__ __launch_bounds__(256) void kan1_gemm_kernel(
    const float* __restrict__ x1, const float* __restrict__ Ct,
    const int* __restrict__ dimt, const float* __restrict__ wkt, const float* __restrict__ pht,
    float* __restrict__ pmax, float* __restrict__ psump) {
  __shared__ float smem[14464];      // 57.8 KB
  float* x1t = smem;                 // [128][65]  transposed x1 tile
  float* At  = smem + 8320;          // [32][64]   A^T (kk-major)
  float* Bt  = smem + 10368;         // [32][128]
  int tid = threadIdx.x;
  int bm = blockIdx.x, bn = blockIdx.y;
  int m0 = bm * 64, n0 = bn * 128;
  for (int m = 0; m < 8; ++m) {
    int flat = tid + 256 * m;
    int p = flat >> 5, c4 = flat & 31;
    float4 v = *(const float4*)(x1 + (m0 + p) * 128 + c4 * 4);
    x1t[(c4 * 4 + 0) * 65 + p] = v.x;
    x1t[(c4 * 4 + 1) * 65 + p] = v.y;
    x1t[(c4 * 4 + 2) * 65 + p] = v.z;
    x1t[(c4 * 4 + 3) * 65 + p] = v.w;
  }
  float acc[4][8] = {};
  int ti = tid >> 4, tj = tid & 15;
  __syncthreads();
  for (int j0 = 0; j0 < 2912; j0 += 32) {
    for (int m = 0; m < 4; ++m) {
      int flat = tid + 256 * m;
      int r = flat >> 5, c4 = flat & 31;
      *(float4*)(&Bt[r * 128 + c4 * 4]) = *(const float4*)(Ct + (size_t)(j0 + r) * 1024 + n0 + c4 * 4);
    }
    for (int m = 0; m < 8; ++m) {
      int flat = tid + 256 * m;
      int kk = flat >> 6, pp = flat & 63;
      int j = j0 + kk;
      float ang = x1t[dimt[j] * 65 + pp] * wkt[j] - pht[j];
      At[kk * 64 + pp] = __cosf(ang);
    }
    __syncthreads();
#pragma unroll 8
    for (int kk = 0; kk < 32; ++kk) {
      float4 a  = *(const float4*)(&At[kk * 64 + ti * 4]);
      float4 b0 = *(const float4*)(&Bt[kk * 128 + tj * 8]);
      float4 b1 = *(const float4*)(&Bt[kk * 128 + tj * 8 + 4]);
      float av[4] = {a.x, a.y, a.z, a.w};
      float bv[8] = {b0.x, b0.y, b0.z, b0.w, b1.x, b1.y, b1.z, b1.w};
#pragma unroll
      for (int i = 0; i < 4; ++i)
#pragma unroll
        for (int jj = 0; jj < 8; ++jj) acc[i][jj] += av[i] * bv[jj];
    }
    __syncthreads();
  }
  // epilogue: per-block max/sum over the 64 rows (all same graph), reuse At/Bt space
  float* rmax = smem + 8320;         // [16][128]
  float* rsum = smem + 8320 + 2048;  // [16][128]
  for (int jj = 0; jj < 8; ++jj) {
    float mx = acc[0][jj], sm = acc[0][jj];
#pragma unroll
    for (int i = 1; i < 4; ++i) { mx = fmaxf(mx, acc[i][jj]); sm += acc[i][jj]; }
    rmax[ti * 128 + tj * 8 + jj] = mx;
    rsum[ti * 128 + tj * 8 + jj] = sm;
  }
  __syncthreads();
  for (int s = 8; s >= 1; s >>= 1) {
    if (ti < s) {
#pragma unroll
      for (int jj = 0; jj < 8; ++jj) {
        int col = tj * 8 + jj;
        rmax[ti * 128 + col] = fmaxf(rmax[ti * 128 + col], rmax[(ti + s) * 128 + col]);
        rsum[ti * 128 + col] += rsum[(ti + s) * 128 + col];
      }
    }
    __syncthreads();
  }
  if (ti == 0) {
#pragma unroll
    for (int jj = 0; jj < 8; ++jj) {
      int col = tj * 8 + jj;
      pmax[(size_t)bm * 1024 + n0 + col]  = rmax[col];
      psump[(size_t)bm * 1024 + n0 + col] = rsum[col];
    }
  }
}

// ---------------- final pool: 16 partials -> gmax/gmean (+bi1) ----------------
__global__ void pool_reduce_kernel(const float* __restrict__ pmax, const float* __restrict__ psump,
                                   const float* __restrict__ bi1,
                                   float* __restrict__ gmax, float* __restrict__ gmean) {
  int gid = blockIdx.x * 256 + threadIdx.x;   // 32768 = 32 graphs x 1024 cols
  int b = gid >> 10, col = gid & 1023;
  float mx = -1e30f, sm = 0.f;
  for (int t = 0; t < 16; ++t) {
    mx = fmaxf(mx, pmax[(size_t)(b * 16 + t) * 1024 + col]);
    sm += psump[(size_t)(b * 16 + t) * 1024 + col];
  }
  float bias = bi1[col];
  gmax[gid] = mx + bias;
  gmean[gid] = sm * (1.0f / 1024.0f) + bias;
}

// ---------------- STFT-KAN2: xcat [32,2048] -> out [32,7] ----------------
__global__ __launch_bounds__(256) void kan2_kernel(
    const float* __restrict__ gmax, const float* __restrict__ gmean,
    const float* __restrict__ c2, const float* __restrict__ bi2,
    float* __restrict__ out) {
  __shared__ float xc[2048];
  __shared__ float hw[197];
  __shared__ float racc[7][256];
  int b = blockIdx.x, tid = threadIdx.x;
  for (int f = tid; f < 1024; f += 256) {
    xc[f] = gmax[b * 1024 + f];
    xc[1024 + f] = gmean[b * 1024 + f];
  }
  for (int f = tid; f < 197; f += 256)
    hw[f] = 0.5f * (1.0f - cosf(6.283185307179586f * (float)f / 197.0f));
  float acc[7] = {};
  __syncthreads();
  for (int q = tid; q < 52205; q += 256) {   // 265 windows x 197 taps
    int n = q / 197;
    int w = q - n * 197;
    float xw = xc[n * 7 + w] * hw[w];
    float s1, c1v;
    sincosf(xw, &s1, &c1v);
    float ckv[6], skv[6];
    ckv[0] = c1v; skv[0] = s1;
#pragma unroll
    for (int g = 1; g < 6; ++g) {
      ckv[g] = ckv[g - 1] * c1v - skv[g - 1] * s1;
      skv[g] = skv[g - 1] * c1v + ckv[g - 1] * s1;   // careful: uses updated ck? no -> fix below
    }
    // recompute sk correctly (the line above used the already-updated ck)
    // do it cleanly:
    {
      float ck = c1v, sk = s1;
#pragma unroll
      for (int g = 0; g < 6; ++g) {
        ckv[g] = ck; skv[g] = sk;
        float cn = ck * c1v - sk * s1;
        sk = sk * c1v + ck * s1;
        ck = cn;
      }
    }
    int base = q * 6;
#pragma unroll
    for (int o = 0; o < 7; ++o) {
      const float* pc = c2 + o * 313230 + base;
      const float* ps = c2 + (o + 7) * 313230 + base;
      float sc = 0.f, ss = 0.f;
#pragma unroll
      for (int g = 0; g < 6; ++g) { sc += ckv[g] * pc[g]; ss += skv[g] * ps[g]; }
      acc[o] += sc + ss;
    }
  }
#pragma unroll
  for (int o = 0; o < 7; ++o) racc[o][tid] = acc[o];
  __syncthreads();
  for (int s = 128; s >= 1; s >>= 1) {
    if (tid < s)
#pragma unroll
      for (int o = 0; o < 7; ++o) racc[o][tid] += racc[o][tid + s];
    __syncthreads();
  }
  if (tid < 7) out[b * 7 + tid] = racc[tid][0] + bi2[tid];
}

// ---------------------------------------------------------------------------
extern "C" void kernel_launch(void* const* d_in, const int* in_sizes, int n_in,
                              void* d_out, int out_size, void* d_ws, size_t ws_size,
                              hipStream_t stream) {
  const float* pos    = (const float*)d_in[0];
  // d_in[1] = batch (sorted, equal-size graphs) -- not needed
  const float* W1     = (const float*)d_in[2];
  const float* b1     = (const float*)d_in[3];
  const float* gamma1 = (const float*)d_in[4];
  const float* beta1  = (const float*)d_in[5];
  const float* W2     = (const float*)d_in[6];
  const float* b2     = (const float*)d_in[7];
  const float* c1     = (const float*)d_in[8];
  const float* bi1    = (const float*)d_in[9];
  const float* c2     = (const float*)d_in[10];
  const float* bi2    = (const float*)d_in[11];
  float* out = (float*)d_out;
  char* ws = (char*)d_ws;

  int*   nbr   = (int*)  (ws + 0);         // 32768*20*4      = 2,621,440
  float* x1    = (float*)(ws + 2621440);   // 32768*128*4     = 16,777,216
  float* Ct    = (float*)(ws + 19398656);  // 2912*1024*4     = 11,927,552
  int*   dimt  = (int*)  (ws + 31326208);  // 2912*4
  float* wkt   = (float*)(ws + 31337856);  // 2912*4
  float* pht   = (float*)(ws + 31349504);  // 2912*4
  float* psum  = (float*)(ws + 31361152);  // 512*64*4        = 131,072
  float* psq   = (float*)(ws + 31492224);  // 131,072
  float* bns   = (float*)(ws + 31623296);  // 256
  float* bnh   = (float*)(ws + 31623552);  // 256
  float* pmax  = (float*)(ws + 31623808);  // 512*1024*4      = 2,097,152
  float* psump = (float*)(ws + 33720960);  // 2,097,152
  float* gmax  = (float*)(ws + 35818112);  // 32*1024*4       = 131,072
  float* gmean = (float*)(ws + 35949184);  // 131,072
  if (ws_size < 36080256) return;          // insufficient scratch -> fail loudly

  knn_kernel<<<32768, 256, 0, stream>>>(pos, nbr);
  kan1_tables_kernel<<<12, 256, 0, stream>>>(dimt, wkt, pht);
  c1_transpose_kernel<<<11648, 256, 0, stream>>>(c1, Ct);
  edge_stats_kernel<<<512, 256, 0, stream>>>(pos, nbr, W1, b1, psum, psq);
  bn_finalize_kernel<<<1, 64, 0, stream>>>(psum, psq, gamma1, beta1, bns, bnh);
  edge_mlp_kernel<<<8192, 256, 0, stream>>>(pos, nbr, W1, b1, bns, bnh, W2, b2, x1);
  kan1_gemm_kernel<<<dim3(512, 8), 256, 0, stream>>>(x1, Ct, dimt, wkt, pht, pmax, psump);
  pool_reduce_kernel<<<128, 256, 0, stream>>>(pmax, psump, bi1, gmax, gmean);
  kan2_kernel<<<32, 256, 0, stream>>>(gmax, gmean, c2, bi2, out);
}

// Round 2
// 1104.901 us; speedup vs baseline: 3.6186x; 3.6186x over previous
//
#include <hip/hip_runtime.h>
#include <cstdint>

typedef _Float16 half8 __attribute__((ext_vector_type(8)));
typedef float f32x4 __attribute__((ext_vector_type(4)));

__device__ __forceinline__ void gload16(const void* g, void* l) {
  __builtin_amdgcn_global_load_lds(
      (const __attribute__((address_space(1))) void*)g,
      (__attribute__((address_space(3))) void*)l, 16, 0, 0);
}

// ---------------- kNN: one block per point ----------------
__global__ __launch_bounds__(256) void knn_kernel(const float* __restrict__ pos,
                                                  int* __restrict__ nbr) {
  __shared__ float px[1024], py[1024], pz[1024], sq[1024], d2[1024];
  __shared__ float wmin[4];
  __shared__ int warg[4];
  int bid = blockIdx.x;                // global point id
  int b = bid >> 10, n = bid & 1023;
  int tid = threadIdx.x;
  const float* pg = pos + (size_t)b * 3072;
  for (int m = 0; m < 4; ++m) {
    int j = tid + 256 * m;
    float x = pg[3 * j], y = pg[3 * j + 1], z = pg[3 * j + 2];
    px[j] = x; py[j] = y; pz[j] = z; sq[j] = x * x + y * y + z * z;
  }
  __syncthreads();
  float xi = px[n], yi = py[n], zi = pz[n], si = sq[n];
  for (int m = 0; m < 4; ++m) {
    int j = tid + 256 * m;
    float d = si + sq[j] - 2.0f * (xi * px[j] + yi * py[j] + zi * pz[j]);
    if (j == n) d += 1e10f;
    d2[j] = d;
  }
  __syncthreads();
  for (int kk = 0; kk < 20; ++kk) {
    float bv = 1e30f; int bi_ = 0x7fffffff;
    for (int m = 0; m < 4; ++m) {
      int j = tid + 256 * m;
      float d = d2[j];
      if (d < bv || (d == bv && j < bi_)) { bv = d; bi_ = j; }
    }
    for (int off = 32; off >= 1; off >>= 1) {
      float ov = __shfl_xor(bv, off);
      int   oi = __shfl_xor(bi_, off);
      if (ov < bv || (ov == bv && oi < bi_)) { bv = ov; bi_ = oi; }
    }
    if ((tid & 63) == 0) { wmin[tid >> 6] = bv; warg[tid >> 6] = bi_; }
    __syncthreads();
    if (tid == 0) {
      for (int w = 1; w < 4; ++w)
        if (wmin[w] < bv || (wmin[w] == bv && warg[w] < bi_)) { bv = wmin[w]; bi_ = warg[w]; }
      nbr[bid * 20 + kk] = b * 1024 + bi_;
      d2[bi_] = 1e30f;
    }
    __syncthreads();
  }
}

// ---------------- edge MLP layer1 stats (sum, sumsq per channel) ----------------
__global__ __launch_bounds__(256) void edge_stats_kernel(
    const float* __restrict__ pos, const int* __restrict__ nbr,
    const float* __restrict__ W1, const float* __restrict__ b1v,
    float* __restrict__ psum, float* __restrict__ psq) {
  __shared__ float els[256][6];
  __shared__ float w1s[384];
  __shared__ float b1s[64];
  __shared__ float red[8][64];
  int tid = threadIdx.x, bid = blockIdx.x;
  for (int f = tid; f < 384; f += 256) w1s[f] = W1[f];
  if (tid < 64) b1s[tid] = b1v[tid];
  int c = tid & 63, grp = tid >> 6;
  float s = 0.f, s2 = 0.f;
  for (int ch = 0; ch < 5; ++ch) {
    int E = bid * 1280 + ch * 256 + tid;
    int p = E / 20;
    int j = nbr[E];
    float pix = pos[3 * p], piy = pos[3 * p + 1], piz = pos[3 * p + 2];
    float e3 = pos[3 * j] - pix, e4 = pos[3 * j + 1] - piy, e5 = pos[3 * j + 2] - piz;
    __syncthreads();
    els[tid][0] = pix; els[tid][1] = piy; els[tid][2] = piz;
    els[tid][3] = e3;  els[tid][4] = e4;  els[tid][5] = e5;
    __syncthreads();
    for (int m = 0; m < 64; ++m) {
      int e = grp * 64 + m;
      float h = b1s[c];
#pragma unroll
      for (int d = 0; d < 6; ++d) h += els[e][d] * w1s[d * 64 + c];
      s += h; s2 += h * h;
    }
  }
  red[grp][c] = s;
  __syncthreads();
  red[4 + grp][c] = s2;
  __syncthreads();
  if (tid < 64) {
    float S = red[0][tid] + red[1][tid] + red[2][tid] + red[3][tid];
    float Q = red[4][tid] + red[5][tid] + red[6][tid] + red[7][tid];
    psum[bid * 64 + tid] = S;
    psq[bid * 64 + tid] = Q;
  }
}

__global__ void bn_finalize_kernel(const float* __restrict__ psum, const float* __restrict__ psq,
                                   const float* __restrict__ gamma, const float* __restrict__ beta,
                                   float* __restrict__ bns, float* __restrict__ bnh) {
  int c = threadIdx.x;   // 64 threads
  float s = 0.f, q = 0.f;
  for (int b = 0; b < 512; ++b) { s += psum[b * 64 + c]; q += psq[b * 64 + c]; }
  const float inv = 1.0f / 655360.0f;
  float mu = s * inv;
  float var = q * inv - mu * mu;
  float sc = gamma[c] * rsqrtf(var + 1e-5f);
  bns[c] = sc;
  bnh[c] = beta[c] - mu * sc;
}

// ---------------- edge MLP full + max over K -> x1 [32768,128] ----------------
__global__ __launch_bounds__(256) void edge_mlp_kernel(
    const float* __restrict__ pos, const int* __restrict__ nbr,
    const float* __restrict__ W1, const float* __restrict__ b1v,
    const float* __restrict__ bns, const float* __restrict__ bnh,
    const float* __restrict__ W2, const float* __restrict__ b2v,
    float* __restrict__ x1) {
  __shared__ float Hl[80][65];
  __shared__ float w2s[64][128];
  __shared__ float w1s[384];
  __shared__ float b1s[64], scs[64], shs[64];
  int tid = threadIdx.x, bid = blockIdx.x;
  for (int f = tid; f < 8192; f += 256) ((float*)w2s)[f] = W2[f];
  for (int f = tid; f < 384; f += 256) w1s[f] = W1[f];
  if (tid < 64) { b1s[tid] = b1v[tid]; scs[tid] = bns[tid]; shs[tid] = bnh[tid]; }
  int d = tid & 63;
  __syncthreads();
  for (int m = 0; m < 20; ++m) {
    int flat = tid + 256 * m;
    int row = flat >> 6;            // 0..79
    int j = nbr[bid * 80 + row];
    int P = bid * 4 + (row / 20);
    float pix = pos[3 * P], piy = pos[3 * P + 1], piz = pos[3 * P + 2];
    float e3 = pos[3 * j] - pix, e4 = pos[3 * j + 1] - piy, e5 = pos[3 * j + 2] - piz;
    float h = b1s[d];
    h += pix * w1s[d] + piy * w1s[64 + d] + piz * w1s[128 + d]
       + e3 * w1s[192 + d] + e4 * w1s[256 + d] + e5 * w1s[320 + d];
    h = scs[d] * h + shs[d];
    Hl[row][d] = fmaxf(h, 0.f);
  }
  __syncthreads();
  int p = tid >> 6;
  int khalf = (tid >> 5) & 1;
  int cgrp = tid & 31;
  float best[4] = {-1e30f, -1e30f, -1e30f, -1e30f};
  for (int kb = khalf * 2; kb < khalf * 2 + 2; ++kb) {
    float acc[5][4] = {};
    for (int dd = 0; dd < 64; ++dd) {
      float4 wv = *(const float4*)(&w2s[dd][cgrp * 4]);
#pragma unroll
      for (int k5 = 0; k5 < 5; ++k5) {
        float hv = Hl[p * 20 + kb * 5 + k5][dd];
        acc[k5][0] += hv * wv.x; acc[k5][1] += hv * wv.y;
        acc[k5][2] += hv * wv.z; acc[k5][3] += hv * wv.w;
      }
    }
#pragma unroll
    for (int k5 = 0; k5 < 5; ++k5)
#pragma unroll
      for (int q = 0; q < 4; ++q) best[q] = fmaxf(best[q], acc[k5][q]);
  }
#pragma unroll
  for (int q = 0; q < 4; ++q) best[q] = fmaxf(best[q], __shfl_xor(best[q], 32));
  if (khalf == 0) {
    float4 o;
    o.x = best[0] + b2v[cgrp * 4 + 0];
    o.y = best[1] + b2v[cgrp * 4 + 1];
    o.z = best[2] + b2v[cgrp * 4 + 2];
    o.w = best[3] + b2v[cgrp * 4 + 3];
    *(float4*)(&x1[(bid * 4 + p) * 128 + cgrp * 4]) = o;
  }
}

// ---------------- KAN1 tables (padded to 2944): j -> (input dim, window*k) ----------------
__global__ void kan1_tables_kernel(int* __restrict__ dimt, float* __restrict__ wkt) {
  int j = blockIdx.x * 256 + threadIdx.x;
  if (j >= 2944) return;
  if (j >= 2912) { dimt[j] = 0; wkt[j] = 0.0f; return; }
  int r = j % 1456;
  int n = r / 364, r2 = r % 364;
  int w = r2 / 7, g = r2 % 7;
  dimt[j] = n * 20 + w;
  float bart = 1.0f - fabsf(2.0f * (float)w / 52.0f - 1.0f);
  wkt[j] = bart * (float)(g + 1);
}

// ---------------- c1 [2,1024,4,52,7] -> Cf16 [1024][2944] (o-major, zero pad) ----------------
__global__ void c1_to_f16_kernel(const float* __restrict__ c1, _Float16* __restrict__ Cf) {
  int L = blockIdx.x * 256 + threadIdx.x;
  if (L >= 1024 * 2944) return;
  int o = L / 2944, j = L % 2944;
  float v = 0.0f;
  if (j < 2912) {
    int t = j / 1456, r = j % 1456;
    v = c1[(size_t)(t * 1024 + o) * 1456 + r];
  }
  Cf[L] = (_Float16)v;
}

// ---------------- KAN1 MFMA GEMM [32768,2944]x[2944,1024], A = trig on the fly ----------------
// BM=128 BN=256 BK=64, 512 thr (8 waves, 2x4), wave tile 64x64 (4x4 16x16x32 frags).
// Fused per-block max/sum pooling epilogue.
__global__ __launch_bounds__(512) void kan1_gemm_kernel(
    const float* __restrict__ x1, const _Float16* __restrict__ Cf,
    const int* __restrict__ dimt, const float* __restrict__ wkt,
    float* __restrict__ pmax, float* __restrict__ psump) {
  __shared__ __align__(16) _Float16 Asm[128 * 64];   // swizzled row-major [row][k-slot^]
  __shared__ __align__(16) _Float16 Bsm[256 * 64];   // swizzled col-major [col][k-slot^]
  __shared__ int   tdim[2][64];
  __shared__ float twk[2][64];
  __shared__ float pooled[2][2][256];                // [wr][max|sum][col]
  int tid = threadIdx.x;
  int bm = blockIdx.x, bn = blockIdx.y;
  int m0 = bm << 7, n0 = bn << 8;
  int wave = tid >> 6, lane = tid & 63;
  int wr = wave >> 2, wc = wave & 3;
  int l15 = lane & 15, l4 = lane >> 4;

  if (tid < 64) { tdim[0][tid] = dimt[tid]; twk[0][tid] = wkt[tid]; }
  f32x4 acc[4][4] = {};
  __syncthreads();

  for (int t = 0; t < 46; ++t) {
    int j0 = t << 6;
    // ---- stage B tile via global_load_lds (linear LDS dest, pre-swizzled source) ----
#pragma unroll
    for (int i = 0; i < 4; ++i) {
      int idx = i * 512 + tid;          // 0..2047 : col = idx>>3, slot = idx&7
      int col = idx >> 3, slot = idx & 7;
      int sslot = slot ^ (col & 7);
      const _Float16* src = Cf + (size_t)(n0 + col) * 2944 + j0 + sslot * 8;
      gload16(src, (char*)Bsm + idx * 16);
    }
    // ---- stage next step's tables ----
    if (t < 45 && tid < 64) {
      tdim[(t + 1) & 1][tid] = dimt[j0 + 64 + tid];
      twk[(t + 1) & 1][tid] = wkt[j0 + 64 + tid];
    }
    // ---- A-gen: cos(x*wk - phase) -> swizzled LDS ----
    const int* td = tdim[t & 1];
    const float* tw = twk[t & 1];
#pragma unroll
    for (int rep = 0; rep < 2; ++rep) {
      int slot = tid + rep * 512;       // 0..1023 : r = slot>>3, s = slot&7
      int r = slot >> 3, s = slot & 7;
      const float* xrow = x1 + (size_t)(m0 + r) * 128;
      int d0 = td[s * 8], d7 = td[s * 8 + 7];
      float x0 = xrow[d0], x7 = xrow[d7];
      half8 av;
#pragma unroll
      for (int e = 0; e < 8; ++e) {
        int jj = s * 8 + e;
        float xv = (td[jj] == d0) ? x0 : x7;
        float ph = (j0 + jj >= 1456) ? 1.57079632679489662f : 0.0f;
        av[e] = (_Float16)__cosf(xv * tw[jj] - ph);
      }
      *(half8*)((char*)Asm + r * 128 + ((s ^ (r & 7)) << 4)) = av;
    }
    __syncthreads();
    // ---- MFMA ----
#pragma unroll
    for (int ksub = 0; ksub < 2; ++ksub) {
      int slotk = ksub * 4 + l4;
      half8 af[4], bf[4];
#pragma unroll
      for (int mi = 0; mi < 4; ++mi) {
        int row = wr * 64 + mi * 16 + l15;
        af[mi] = *(const half8*)((char*)Asm + row * 128 + ((slotk ^ (row & 7)) << 4));
      }
#pragma unroll
      for (int ni = 0; ni < 4; ++ni) {
        int col = wc * 64 + ni * 16 + l15;
        bf[ni] = *(const half8*)((char*)Bsm + col * 128 + ((slotk ^ (col & 7)) << 4));
      }
#pragma unroll
      for (int mi = 0; mi < 4; ++mi)
#pragma unroll
        for (int ni = 0; ni < 4; ++ni)
          acc[mi][ni] = __builtin_amdgcn_mfma_f32_16x16x32_f16(af[mi], bf[ni], acc[mi][ni], 0, 0, 0);
    }
    __syncthreads();
  }

  // ---- fused pooling epilogue: max/sum over the block's 128 rows ----
  // lane's acc element (mi,ni,q): row = wr*64 + mi*16 + l4*4 + q, col = wc*64 + ni*16 + l15
#pragma unroll
  for (int ni = 0; ni < 4; ++ni) {
    float mx = -1e30f, sm = 0.f;
#pragma unroll
    for (int mi = 0; mi < 4; ++mi)
#pragma unroll
      for (int q = 0; q < 4; ++q) {
        float v = acc[mi][ni][q];
        mx = fmaxf(mx, v); sm += v;
      }
    mx = fmaxf(mx, __shfl_xor(mx, 16)); sm += __shfl_xor(sm, 16);
    mx = fmaxf(mx, __shfl_xor(mx, 32)); sm += __shfl_xor(sm, 32);
    if (l4 == 0) {
      int col = wc * 64 + ni * 16 + l15;
      pooled[wr][0][col] = mx;
      pooled[wr][1][col] = sm;
    }
  }
  __syncthreads();
  if (tid < 256) {
    float mx = fmaxf(pooled[0][0][tid], pooled[1][0][tid]);
    float sm = pooled[0][1][tid] + pooled[1][1][tid];
    pmax[(size_t)bm * 1024 + n0 + tid] = mx;
    psump[(size_t)bm * 1024 + n0 + tid] = sm;
  }
}

// ---------------- final pool: 8 m-block partials -> gmax/gmean (+bi1) ----------------
__global__ void pool_reduce_kernel(const float* __restrict__ pmax, const float* __restrict__ psump,
                                   const float* __restrict__ bi1,
                                   float* __restrict__ gmax, float* __restrict__ gmean) {
  int gid = blockIdx.x * 256 + threadIdx.x;   // 32768 = 32 graphs x 1024 cols
  int b = gid >> 10, col = gid & 1023;
  float mx = -1e30f, sm = 0.f;
  for (int t = 0; t < 8; ++t) {
    mx = fmaxf(mx, pmax[(size_t)(b * 8 + t) * 1024 + col]);
    sm += psump[(size_t)(b * 8 + t) * 1024 + col];
  }
  float bias = bi1[col];
  gmax[gid] = mx + bias;
  gmean[gid] = sm * (1.0f / 1024.0f) + bias;
}

// ---------------- STFT-KAN2 partials: xcat [32,2048] -> part [32,16,7] ----------------
__global__ __launch_bounds__(256) void kan2_kernel(
    const float* __restrict__ gmax, const float* __restrict__ gmean,
    const float* __restrict__ c2, float* __restrict__ part) {
  __shared__ float xc[2048];
  __shared__ float hw[197];
  __shared__ float racc[7][256];
  int b = blockIdx.x, s = blockIdx.y, tid = threadIdx.x;
  for (int f = tid; f < 1024; f += 256) {
    xc[f] = gmax[b * 1024 + f];
    xc[1024 + f] = gmean[b * 1024 + f];
  }
  for (int f = tid; f < 197; f += 256)
    hw[f] = 0.5f * (1.0f - cosf(6.283185307179586f * (float)f / 197.0f));
  float acc[7] = {};
  __syncthreads();
  int qlo = (52205 * s) / 16, qhi = (52205 * (s + 1)) / 16;
  for (int q = qlo + tid; q < qhi; q += 256) {   // 265 windows x 197 taps
    int n = q / 197;
    int w = q - n * 197;
    float xw = xc[n * 7 + w] * hw[w];
    float s1, c1v;
    __sincosf(xw, &s1, &c1v);
    float ckv[6], skv[6];
    {
      float ck = c1v, sk = s1;
#pragma unroll
      for (int g = 0; g < 6; ++g) {
        ckv[g] = ck; skv[g] = sk;
        float cn = ck * c1v - sk * s1;
        sk = sk * c1v + ck * s1;
        ck = cn;
      }
    }
    int base = q * 6;
#pragma unroll
    for (int o = 0; o < 7; ++o) {
      const float* pc = c2 + (size_t)o * 313230 + base;
      const float* ps = c2 + (size_t)(o + 7) * 313230 + base;
      float sc = 0.f, ss = 0.f;
#pragma unroll
      for (int g = 0; g < 6; ++g) { sc += ckv[g] * pc[g]; ss += skv[g] * ps[g]; }
      acc[o] += sc + ss;
    }
  }
#pragma unroll
  for (int o = 0; o < 7; ++o) racc[o][tid] = acc[o];
  __syncthreads();
  for (int st = 128; st >= 1; st >>= 1) {
    if (tid < st)
#pragma unroll
      for (int o = 0; o < 7; ++o) racc[o][tid] += racc[o][tid + st];
    __syncthreads();
  }
  if (tid < 7) part[(b * 16 + s) * 7 + tid] = racc[tid][0];
}

__global__ void kan2_reduce_kernel(const float* __restrict__ part, const float* __restrict__ bi2,
                                   float* __restrict__ out) {
  int i = threadIdx.x;   // 224 threads: (b, o)
  if (i >= 224) return;
  int b = i / 7, o = i % 7;
  float s = 0.f;
  for (int t = 0; t < 16; ++t) s += part[(b * 16 + t) * 7 + o];
  out[b * 7 + o] = s + bi2[o];
}

// ---------------------------------------------------------------------------
extern "C" void kernel_launch(void* const* d_in, const int* in_sizes, int n_in,
                              void* d_out, int out_size, void* d_ws, size_t ws_size,
                              hipStream_t stream) {
  const float* pos    = (const float*)d_in[0];
  const float* W1     = (const float*)d_in[2];
  const float* b1     = (const float*)d_in[3];
  const float* gamma1 = (const float*)d_in[4];
  const float* beta1  = (const float*)d_in[5];
  const float* W2     = (const float*)d_in[6];
  const float* b2     = (const float*)d_in[7];
  const float* c1     = (const float*)d_in[8];
  const float* bi1    = (const float*)d_in[9];
  const float* c2     = (const float*)d_in[10];
  const float* bi2    = (const float*)d_in[11];
  float* out = (float*)d_out;
  char* ws = (char*)d_ws;

  int*      nbr   = (int*)     (ws + 0);          // 2,621,440
  float*    x1    = (float*)   (ws + 2621440);    // 16,777,216
  _Float16* Cf    = (_Float16*)(ws + 19398656);   // 1024*2944*2 = 6,029,312
  int*      dimt  = (int*)     (ws + 25427968);   // 11,776
  float*    wkt   = (float*)   (ws + 25439744);   // 11,776
  float*    psum  = (float*)   (ws + 25451520);   // 131,072
  float*    psq   = (float*)   (ws + 25582592);   // 131,072
  float*    bns   = (float*)   (ws + 25713664);   // 256
  float*    bnh   = (float*)   (ws + 25713920);   // 256
  float*    pmax  = (float*)   (ws + 25714176);   // 1,048,576
  float*    psump = (float*)   (ws + 26762752);   // 1,048,576
  float*    gmax  = (float*)   (ws + 27811328);   // 131,072
  float*    gmean = (float*)   (ws + 27942400);   // 131,072
  float*    part  = (float*)   (ws + 28073472);   // 14,336
  if (ws_size < 28087808) return;

  knn_kernel<<<32768, 256, 0, stream>>>(pos, nbr);
  kan1_tables_kernel<<<12, 256, 0, stream>>>(dimt, wkt);
  c1_to_f16_kernel<<<11776, 256, 0, stream>>>(c1, Cf);
  edge_stats_kernel<<<512, 256, 0, stream>>>(pos, nbr, W1, b1, psum, psq);
  bn_finalize_kernel<<<1, 64, 0, stream>>>(psum, psq, gamma1, beta1, bns, bnh);
  edge_mlp_kernel<<<8192, 256, 0, stream>>>(pos, nbr, W1, b1, bns, bnh, W2, b2, x1);
  kan1_gemm_kernel<<<dim3(256, 4), 512, 0, stream>>>(x1, Cf, dimt, wkt, pmax, psump);
  pool_reduce_kernel<<<128, 256, 0, stream>>>(pmax, psump, bi1, gmax, gmean);
  kan2_kernel<<<dim3(32, 16), 256, 0, stream>>>(gmax, gmean, c2, part);
  kan2_reduce_kernel<<<1, 256, 0, stream>>>(part, bi2, out);
}

// Round 3
// 722.019 us; speedup vs baseline: 5.5376x; 1.5303x over previous
//
#include <hip/hip_runtime.h>
#include <cstdint>

typedef _Float16 half8 __attribute__((ext_vector_type(8)));
typedef float f32x4 __attribute__((ext_vector_type(4)));

__device__ __forceinline__ void gload16(const void* g, void* l) {
  __builtin_amdgcn_global_load_lds(
      (const __attribute__((address_space(1))) void*)g,
      (__attribute__((address_space(3))) void*)l, 16, 0, 0);
}

// ---------------- kNN: one WAVE per query point, barrier-free selection ----------------
// Block = 4 waves = 4 query points of one graph. Each lane holds 16 candidate
// distances in registers; 20 rounds of reg-argmin + shfl butterfly (no syncthreads).
__global__ __launch_bounds__(256) void knn_kernel(const float* __restrict__ pos,
                                                  int* __restrict__ nbr) {
  __shared__ float px[1024], py[1024], pz[1024], sq[1024];
  int tid = threadIdx.x;
  int b = blockIdx.x >> 8;                 // graph id (256 blocks per graph)
  const float* pg = pos + (size_t)b * 3072;
  for (int m = 0; m < 4; ++m) {
    int j = m * 256 + tid;
    float x = pg[3 * j], y = pg[3 * j + 1], z = pg[3 * j + 2];
    px[j] = x; py[j] = y; pz[j] = z; sq[j] = x * x + y * y + z * z;
  }
  __syncthreads();
  int wave = tid >> 6, lane = tid & 63;
  int n = (blockIdx.x & 255) * 4 + wave;   // local query index in graph
  float xi = px[n], yi = py[n], zi = pz[n], si = sq[n];
  float d[16];
#pragma unroll
  for (int i = 0; i < 16; ++i) {
    int j = i * 64 + lane;
    float dd = si + sq[j] - 2.0f * (xi * px[j] + yi * py[j] + zi * pz[j]);
    d[i] = (j == n) ? 1e30f : dd;          // exclude self
  }
  int outbase = (b * 1024 + n) * 20;
  for (int kk = 0; kk < 20; ++kk) {
    // lane-local argmin over 16 regs (strict < -> lowest index on ties)
    float lmin = d[0]; int lpos = 0;
#pragma unroll
    for (int i = 1; i < 16; ++i)
      if (d[i] < lmin) { lmin = d[i]; lpos = i; }
    float bv = lmin; int bi = lpos * 64 + lane;
    // wave butterfly min with (value, index) tie-break
#pragma unroll
    for (int off = 1; off < 64; off <<= 1) {
      float ov = __shfl_xor(bv, off);
      int   oi = __shfl_xor(bi, off);
      if (ov < bv || (ov == bv && oi < bi)) { bv = ov; bi = oi; }
    }
    if (lane == 0) nbr[outbase + kk] = b * 1024 + bi;
    // owning lane removes the winner (compile-time-indexed predicated clear)
    if ((bi & 63) == lane) {
      int rp = bi >> 6;
#pragma unroll
      for (int i = 0; i < 16; ++i)
        if (i == rp) d[i] = 1e30f;
    }
  }
}

// ---------------- edge MLP layer1 stats (sum, sumsq per channel) ----------------
__global__ __launch_bounds__(256) void edge_stats_kernel(
    const float* __restrict__ pos, const int* __restrict__ nbr,
    const float* __restrict__ W1, const float* __restrict__ b1v,
    float* __restrict__ psum, float* __restrict__ psq) {
  __shared__ float els[256][6];
  __shared__ float w1s[384];
  __shared__ float b1s[64];
  __shared__ float red[8][64];
  int tid = threadIdx.x, bid = blockIdx.x;
  for (int f = tid; f < 384; f += 256) w1s[f] = W1[f];
  if (tid < 64) b1s[tid] = b1v[tid];
  int c = tid & 63, grp = tid >> 6;
  float s = 0.f, s2 = 0.f;
  for (int ch = 0; ch < 5; ++ch) {
    int E = bid * 1280 + ch * 256 + tid;
    int p = E / 20;
    int j = nbr[E];
    float pix = pos[3 * p], piy = pos[3 * p + 1], piz = pos[3 * p + 2];
    float e3 = pos[3 * j] - pix, e4 = pos[3 * j + 1] - piy, e5 = pos[3 * j + 2] - piz;
    __syncthreads();
    els[tid][0] = pix; els[tid][1] = piy; els[tid][2] = piz;
    els[tid][3] = e3;  els[tid][4] = e4;  els[tid][5] = e5;
    __syncthreads();
    for (int m = 0; m < 64; ++m) {
      int e = grp * 64 + m;
      float h = b1s[c];
#pragma unroll
      for (int d = 0; d < 6; ++d) h += els[e][d] * w1s[d * 64 + c];
      s += h; s2 += h * h;
    }
  }
  red[grp][c] = s;
  __syncthreads();
  red[4 + grp][c] = s2;
  __syncthreads();
  if (tid < 64) {
    float S = red[0][tid] + red[1][tid] + red[2][tid] + red[3][tid];
    float Q = red[4][tid] + red[5][tid] + red[6][tid] + red[7][tid];
    psum[bid * 64 + tid] = S;
    psq[bid * 64 + tid] = Q;
  }
}

__global__ void bn_finalize_kernel(const float* __restrict__ psum, const float* __restrict__ psq,
                                   const float* __restrict__ gamma, const float* __restrict__ beta,
                                   float* __restrict__ bns, float* __restrict__ bnh) {
  int c = threadIdx.x;   // 64 threads
  float s = 0.f, q = 0.f;
  for (int b = 0; b < 512; ++b) { s += psum[b * 64 + c]; q += psq[b * 64 + c]; }
  const float inv = 1.0f / 655360.0f;
  float mu = s * inv;
  float var = q * inv - mu * mu;
  float sc = gamma[c] * rsqrtf(var + 1e-5f);
  bns[c] = sc;
  bnh[c] = beta[c] - mu * sc;
}

// ---------------- edge MLP full + max over K -> x1 [32768,128] ----------------
__global__ __launch_bounds__(256) void edge_mlp_kernel(
    const float* __restrict__ pos, const int* __restrict__ nbr,
    const float* __restrict__ W1, const float* __restrict__ b1v,
    const float* __restrict__ bns, const float* __restrict__ bnh,
    const float* __restrict__ W2, const float* __restrict__ b2v,
    float* __restrict__ x1) {
  __shared__ float Hl[80][65];
  __shared__ float w2s[64][128];
  __shared__ float w1s[384];
  __shared__ float b1s[64], scs[64], shs[64];
  int tid = threadIdx.x, bid = blockIdx.x;
  for (int f = tid; f < 8192; f += 256) ((float*)w2s)[f] = W2[f];
  for (int f = tid; f < 384; f += 256) w1s[f] = W1[f];
  if (tid < 64) { b1s[tid] = b1v[tid]; scs[tid] = bns[tid]; shs[tid] = bnh[tid]; }
  int d = tid & 63;
  __syncthreads();
  for (int m = 0; m < 20; ++m) {
    int flat = tid + 256 * m;
    int row = flat >> 6;            // 0..79
    int j = nbr[bid * 80 + row];
    int P = bid * 4 + (row / 20);
    float pix = pos[3 * P], piy = pos[3 * P + 1], piz = pos[3 * P + 2];
    float e3 = pos[3 * j] - pix, e4 = pos[3 * j + 1] - piy, e5 = pos[3 * j + 2] - piz;
    float h = b1s[d];
    h += pix * w1s[d] + piy * w1s[64 + d] + piz * w1s[128 + d]
       + e3 * w1s[192 + d] + e4 * w1s[256 + d] + e5 * w1s[320 + d];
    h = scs[d] * h + shs[d];
    Hl[row][d] = fmaxf(h, 0.f);
  }
  __syncthreads();
  int p = tid >> 6;
  int khalf = (tid >> 5) & 1;
  int cgrp = tid & 31;
  float best[4] = {-1e30f, -1e30f, -1e30f, -1e30f};
  for (int kb = khalf * 2; kb < khalf * 2 + 2; ++kb) {
    float acc[5][4] = {};
    for (int dd = 0; dd < 64; ++dd) {
      float4 wv = *(const float4*)(&w2s[dd][cgrp * 4]);
#pragma unroll
      for (int k5 = 0; k5 < 5; ++k5) {
        float hv = Hl[p * 20 + kb * 5 + k5][dd];
        acc[k5][0] += hv * wv.x; acc[k5][1] += hv * wv.y;
        acc[k5][2] += hv * wv.z; acc[k5][3] += hv * wv.w;
      }
    }
#pragma unroll
    for (int k5 = 0; k5 < 5; ++k5)
#pragma unroll
      for (int q = 0; q < 4; ++q) best[q] = fmaxf(best[q], acc[k5][q]);
  }
#pragma unroll
  for (int q = 0; q < 4; ++q) best[q] = fmaxf(best[q], __shfl_xor(best[q], 32));
  if (khalf == 0) {
    float4 o;
    o.x = best[0] + b2v[cgrp * 4 + 0];
    o.y = best[1] + b2v[cgrp * 4 + 1];
    o.z = best[2] + b2v[cgrp * 4 + 2];
    o.w = best[3] + b2v[cgrp * 4 + 3];
    *(float4*)(&x1[(bid * 4 + p) * 128 + cgrp * 4]) = o;
  }
}

// ---------------- KAN1 tables (padded to 2944): j -> (input dim, window*k) ----------------
__global__ void kan1_tables_kernel(int* __restrict__ dimt, float* __restrict__ wkt) {
  int j = blockIdx.x * 256 + threadIdx.x;
  if (j >= 2944) return;
  if (j >= 2912) { dimt[j] = 0; wkt[j] = 0.0f; return; }
  int r = j % 1456;
  int n = r / 364, r2 = r % 364;
  int w = r2 / 7, g = r2 % 7;
  dimt[j] = n * 20 + w;
  float bart = 1.0f - fabsf(2.0f * (float)w / 52.0f - 1.0f);
  wkt[j] = bart * (float)(g + 1);
}

// ---------------- c1 [2,1024,4,52,7] -> Cf16 [1024][2944] (o-major, zero pad) ----------------
__global__ void c1_to_f16_kernel(const float* __restrict__ c1, _Float16* __restrict__ Cf) {
  int L = blockIdx.x * 256 + threadIdx.x;
  if (L >= 1024 * 2944) return;
  int o = L / 2944, j = L % 2944;
  float v = 0.0f;
  if (j < 2912) {
    int t = j / 1456, r = j % 1456;
    v = c1[(size_t)(t * 1024 + o) * 1456 + r];
  }
  Cf[L] = (_Float16)v;
}

// ---------------- KAN1 MFMA GEMM [32768,2944]x[2944,1024], A = trig on the fly ----------------
__global__ __launch_bounds__(512) void kan1_gemm_kernel(
    const float* __restrict__ x1, const _Float16* __restrict__ Cf,
    const int* __restrict__ dimt, const float* __restrict__ wkt,
    float* __restrict__ pmax, float* __restrict__ psump) {
  __shared__ __align__(16) _Float16 Asm[128 * 64];   // swizzled row-major [row][k-slot^]
  __shared__ __align__(16) _Float16 Bsm[256 * 64];   // swizzled col-major [col][k-slot^]
  __shared__ int   tdim[2][64];
  __shared__ float twk[2][64];
  __shared__ float pooled[2][2][256];                // [wr][max|sum][col]
  int tid = threadIdx.x;
  int bm = blockIdx.x, bn = blockIdx.y;
  int m0 = bm << 7, n0 = bn << 8;
  int wave = tid >> 6, lane = tid & 63;
  int wr = wave >> 2, wc = wave & 3;
  int l15 = lane & 15, l4 = lane >> 4;

  if (tid < 64) { tdim[0][tid] = dimt[tid]; twk[0][tid] = wkt[tid]; }
  f32x4 acc[4][4] = {};
  __syncthreads();

  for (int t = 0; t < 46; ++t) {
    int j0 = t << 6;
#pragma unroll
    for (int i = 0; i < 4; ++i) {
      int idx = i * 512 + tid;          // 0..2047 : col = idx>>3, slot = idx&7
      int col = idx >> 3, slot = idx & 7;
      int sslot = slot ^ (col & 7);
      const _Float16* src = Cf + (size_t)(n0 + col) * 2944 + j0 + sslot * 8;
      gload16(src, (char*)Bsm + idx * 16);
    }
    if (t < 45 && tid < 64) {
      tdim[(t + 1) & 1][tid] = dimt[j0 + 64 + tid];
      twk[(t + 1) & 1][tid] = wkt[j0 + 64 + tid];
    }
    const int* td = tdim[t & 1];
    const float* tw = twk[t & 1];
#pragma unroll
    for (int rep = 0; rep < 2; ++rep) {
      int slot = tid + rep * 512;       // 0..1023 : r = slot>>3, s = slot&7
      int r = slot >> 3, s = slot & 7;
      const float* xrow = x1 + (size_t)(m0 + r) * 128;
      int d0 = td[s * 8], d7 = td[s * 8 + 7];
      float x0 = xrow[d0], x7 = xrow[d7];
      half8 av;
#pragma unroll
      for (int e = 0; e < 8; ++e) {
        int jj = s * 8 + e;
        float xv = (td[jj] == d0) ? x0 : x7;
        float ph = (j0 + jj >= 1456) ? 1.57079632679489662f : 0.0f;
        av[e] = (_Float16)__cosf(xv * tw[jj] - ph);
      }
      *(half8*)((char*)Asm + r * 128 + ((s ^ (r & 7)) << 4)) = av;
    }
    __syncthreads();
#pragma unroll
    for (int ksub = 0; ksub < 2; ++ksub) {
      int slotk = ksub * 4 + l4;
      half8 af[4], bf[4];
#pragma unroll
      for (int mi = 0; mi < 4; ++mi) {
        int row = wr * 64 + mi * 16 + l15;
        af[mi] = *(const half8*)((char*)Asm + row * 128 + ((slotk ^ (row & 7)) << 4));
      }
#pragma unroll
      for (int ni = 0; ni < 4; ++ni) {
        int col = wc * 64 + ni * 16 + l15;
        bf[ni] = *(const half8*)((char*)Bsm + col * 128 + ((slotk ^ (col & 7)) << 4));
      }
#pragma unroll
      for (int mi = 0; mi < 4; ++mi)
#pragma unroll
        for (int ni = 0; ni < 4; ++ni)
          acc[mi][ni] = __builtin_amdgcn_mfma_f32_16x16x32_f16(af[mi], bf[ni], acc[mi][ni], 0, 0, 0);
    }
    __syncthreads();
  }

  // ---- fused pooling epilogue ----
#pragma unroll
  for (int ni = 0; ni < 4; ++ni) {
    float mx = -1e30f, sm = 0.f;
#pragma unroll
    for (int mi = 0; mi < 4; ++mi)
#pragma unroll
      for (int q = 0; q < 4; ++q) {
        float v = acc[mi][ni][q];
        mx = fmaxf(mx, v); sm += v;
      }
    mx = fmaxf(mx, __shfl_xor(mx, 16)); sm += __shfl_xor(sm, 16);
    mx = fmaxf(mx, __shfl_xor(mx, 32)); sm += __shfl_xor(sm, 32);
    if (l4 == 0) {
      int col = wc * 64 + ni * 16 + l15;
      pooled[wr][0][col] = mx;
      pooled[wr][1][col] = sm;
    }
  }
  __syncthreads();
  if (tid < 256) {
    float mx = fmaxf(pooled[0][0][tid], pooled[1][0][tid]);
    float sm = pooled[0][1][tid] + pooled[1][1][tid];
    pmax[(size_t)bm * 1024 + n0 + tid] = mx;
    psump[(size_t)bm * 1024 + n0 + tid] = sm;
  }
}

// ---------------- final pool: 8 m-block partials -> gmax/gmean (+bi1) ----------------
__global__ void pool_reduce_kernel(const float* __restrict__ pmax, const float* __restrict__ psump,
                                   const float* __restrict__ bi1,
                                   float* __restrict__ gmax, float* __restrict__ gmean) {
  int gid = blockIdx.x * 256 + threadIdx.x;   // 32768 = 32 graphs x 1024 cols
  int b = gid >> 10, col = gid & 1023;
  float mx = -1e30f, sm = 0.f;
  for (int t = 0; t < 8; ++t) {
    mx = fmaxf(mx, pmax[(size_t)(b * 8 + t) * 1024 + col]);
    sm += psump[(size_t)(b * 8 + t) * 1024 + col];
  }
  float bias = bi1[col];
  gmax[gid] = mx + bias;
  gmean[gid] = sm * (1.0f / 1024.0f) + bias;
}

// ---------------- STFT-KAN2 partials: xcat [32,2048] -> part [32,16,7] ----------------
__global__ __launch_bounds__(256) void kan2_kernel(
    const float* __restrict__ gmax, const float* __restrict__ gmean,
    const float* __restrict__ c2, float* __restrict__ part) {
  __shared__ float xc[2048];
  __shared__ float hw[197];
  __shared__ float racc[7][256];
  int b = blockIdx.x, s = blockIdx.y, tid = threadIdx.x;
  for (int f = tid; f < 1024; f += 256) {
    xc[f] = gmax[b * 1024 + f];
    xc[1024 + f] = gmean[b * 1024 + f];
  }
  for (int f = tid; f < 197; f += 256)
    hw[f] = 0.5f * (1.0f - cosf(6.283185307179586f * (float)f / 197.0f));
  float acc[7] = {};
  __syncthreads();
  int qlo = (52205 * s) / 16, qhi = (52205 * (s + 1)) / 16;
  for (int q = qlo + tid; q < qhi; q += 256) {
    int n = q / 197;
    int w = q - n * 197;
    float xw = xc[n * 7 + w] * hw[w];
    float s1, c1v;
    __sincosf(xw, &s1, &c1v);
    float ckv[6], skv[6];
    {
      float ck = c1v, sk = s1;
#pragma unroll
      for (int g = 0; g < 6; ++g) {
        ckv[g] = ck; skv[g] = sk;
        float cn = ck * c1v - sk * s1;
        sk = sk * c1v + ck * s1;
        ck = cn;
      }
    }
    int base = q * 6;
#pragma unroll
    for (int o = 0; o < 7; ++o) {
      const float* pc = c2 + (size_t)o * 313230 + base;
      const float* ps = c2 + (size_t)(o + 7) * 313230 + base;
      float sc = 0.f, ss = 0.f;
#pragma unroll
      for (int g = 0; g < 6; ++g) { sc += ckv[g] * pc[g]; ss += skv[g] * ps[g]; }
      acc[o] += sc + ss;
    }
  }
#pragma unroll
  for (int o = 0; o < 7; ++o) racc[o][tid] = acc[o];
  __syncthreads();
  for (int st = 128; st >= 1; st >>= 1) {
    if (tid < st)
#pragma unroll
      for (int o = 0; o < 7; ++o) racc[o][tid] += racc[o][tid + st];
    __syncthreads();
  }
  if (tid < 7) part[(b * 16 + s) * 7 + tid] = racc[tid][0];
}

__global__ void kan2_reduce_kernel(const float* __restrict__ part, const float* __restrict__ bi2,
                                   float* __restrict__ out) {
  int i = threadIdx.x;   // 224 threads: (b, o)
  if (i >= 224) return;
  int b = i / 7, o = i % 7;
  float s = 0.f;
  for (int t = 0; t < 16; ++t) s += part[(b * 16 + t) * 7 + o];
  out[b * 7 + o] = s + bi2[o];
}

// ---------------------------------------------------------------------------
extern "C" void kernel_launch(void* const* d_in, const int* in_sizes, int n_in,
                              void* d_out, int out_size, void* d_ws, size_t ws_size,
                              hipStream_t stream) {
  const float* pos    = (const float*)d_in[0];
  const float* W1     = (const float*)d_in[2];
  const float* b1     = (const float*)d_in[3];
  const float* gamma1 = (const float*)d_in[4];
  const float* beta1  = (const float*)d_in[5];
  const float* W2     = (const float*)d_in[6];
  const float* b2     = (const float*)d_in[7];
  const float* c1     = (const float*)d_in[8];
  const float* bi1    = (const float*)d_in[9];
  const float* c2     = (const float*)d_in[10];
  const float* bi2    = (const float*)d_in[11];
  float* out = (float*)d_out;
  char* ws = (char*)d_ws;

  int*      nbr   = (int*)     (ws + 0);          // 2,621,440
  float*    x1    = (float*)   (ws + 2621440);    // 16,777,216
  _Float16* Cf    = (_Float16*)(ws + 19398656);   // 6,029,312
  int*      dimt  = (int*)     (ws + 25427968);   // 11,776
  float*    wkt   = (float*)   (ws + 25439744);   // 11,776
  float*    psum  = (float*)   (ws + 25451520);   // 131,072
  float*    psq   = (float*)   (ws + 25582592);   // 131,072
  float*    bns   = (float*)   (ws + 25713664);   // 256
  float*    bnh   = (float*)   (ws + 25713920);   // 256
  float*    pmax  = (float*)   (ws + 25714176);   // 1,048,576
  float*    psump = (float*)   (ws + 26762752);   // 1,048,576
  float*    gmax  = (float*)   (ws + 27811328);   // 131,072
  float*    gmean = (float*)   (ws + 27942400);   // 131,072
  float*    part  = (float*)   (ws + 28073472);   // 14,336
  if (ws_size < 28087808) return;

  knn_kernel<<<8192, 256, 0, stream>>>(pos, nbr);
  kan1_tables_kernel<<<12, 256, 0, stream>>>(dimt, wkt);
  c1_to_f16_kernel<<<11776, 256, 0, stream>>>(c1, Cf);
  edge_stats_kernel<<<512, 256, 0, stream>>>(pos, nbr, W1, b1, psum, psq);
  bn_finalize_kernel<<<1, 64, 0, stream>>>(psum, psq, gamma1, beta1, bns, bnh);
  edge_mlp_kernel<<<8192, 256, 0, stream>>>(pos, nbr, W1, b1, bns, bnh, W2, b2, x1);
  kan1_gemm_kernel<<<dim3(256, 4), 512, 0, stream>>>(x1, Cf, dimt, wkt, pmax, psump);
  pool_reduce_kernel<<<128, 256, 0, stream>>>(pmax, psump, bi1, gmax, gmean);
  kan2_kernel<<<dim3(32, 16), 256, 0, stream>>>(gmax, gmean, c2, part);
  kan2_reduce_kernel<<<1, 256, 0, stream>>>(part, bi2, out);
}

// Round 4
// 660.762 us; speedup vs baseline: 6.0509x; 1.0927x over previous
//
#include <hip/hip_runtime.h>
#include <cstdint>

typedef _Float16 half8 __attribute__((ext_vector_type(8)));
typedef float f32x4 __attribute__((ext_vector_type(4)));

__device__ __forceinline__ void gload16(const void* g, void* l) {
  __builtin_amdgcn_global_load_lds(
      (const __attribute__((address_space(1))) void*)g,
      (__attribute__((address_space(3))) void*)l, 16, 0, 0);
}

// ---------------- kNN: one WAVE per query point, barrier-free selection ----------------
__global__ __launch_bounds__(256) void knn_kernel(const float* __restrict__ pos,
                                                  int* __restrict__ nbr) {
  __shared__ float px[1024], py[1024], pz[1024], sq[1024];
  int tid = threadIdx.x;
  int b = blockIdx.x >> 8;                 // graph id (256 blocks per graph)
  const float* pg = pos + (size_t)b * 3072;
  for (int m = 0; m < 4; ++m) {
    int j = m * 256 + tid;
    float x = pg[3 * j], y = pg[3 * j + 1], z = pg[3 * j + 2];
    px[j] = x; py[j] = y; pz[j] = z; sq[j] = x * x + y * y + z * z;
  }
  __syncthreads();
  int wave = tid >> 6, lane = tid & 63;
  int n = (blockIdx.x & 255) * 4 + wave;   // local query index in graph
  float xi = px[n], yi = py[n], zi = pz[n], si = sq[n];
  float d[16];
#pragma unroll
  for (int i = 0; i < 16; ++i) {
    int j = i * 64 + lane;
    float dd = si + sq[j] - 2.0f * (xi * px[j] + yi * py[j] + zi * pz[j]);
    d[i] = (j == n) ? 1e30f : dd;          // exclude self
  }
  int outbase = (b * 1024 + n) * 20;
  for (int kk = 0; kk < 20; ++kk) {
    float lmin = d[0]; int lpos = 0;
#pragma unroll
    for (int i = 1; i < 16; ++i)
      if (d[i] < lmin) { lmin = d[i]; lpos = i; }
    float bv = lmin; int bi = lpos * 64 + lane;
#pragma unroll
    for (int off = 1; off < 64; off <<= 1) {
      float ov = __shfl_xor(bv, off);
      int   oi = __shfl_xor(bi, off);
      if (ov < bv || (ov == bv && oi < bi)) { bv = ov; bi = oi; }
    }
    if (lane == 0) nbr[outbase + kk] = b * 1024 + bi;
    if ((bi & 63) == lane) {
      int rp = bi >> 6;
#pragma unroll
      for (int i = 0; i < 16; ++i)
        if (i == rp) d[i] = 1e30f;
    }
  }
}

// ---------------- edge MLP layer1 stats (sum, sumsq per channel) ----------------
__global__ __launch_bounds__(256) void edge_stats_kernel(
    const float* __restrict__ pos, const int* __restrict__ nbr,
    const float* __restrict__ W1, const float* __restrict__ b1v,
    float* __restrict__ psum, float* __restrict__ psq) {
  __shared__ float els[256][6];
  __shared__ float w1s[384];
  __shared__ float b1s[64];
  __shared__ float red[8][64];
  int tid = threadIdx.x, bid = blockIdx.x;
  for (int f = tid; f < 384; f += 256) w1s[f] = W1[f];
  if (tid < 64) b1s[tid] = b1v[tid];
  int c = tid & 63, grp = tid >> 6;
  float s = 0.f, s2 = 0.f;
  for (int ch = 0; ch < 5; ++ch) {
    int E = bid * 1280 + ch * 256 + tid;
    int p = E / 20;
    int j = nbr[E];
    float pix = pos[3 * p], piy = pos[3 * p + 1], piz = pos[3 * p + 2];
    float e3 = pos[3 * j] - pix, e4 = pos[3 * j + 1] - piy, e5 = pos[3 * j + 2] - piz;
    __syncthreads();
    els[tid][0] = pix; els[tid][1] = piy; els[tid][2] = piz;
    els[tid][3] = e3;  els[tid][4] = e4;  els[tid][5] = e5;
    __syncthreads();
    for (int m = 0; m < 64; ++m) {
      int e = grp * 64 + m;
      float h = b1s[c];
#pragma unroll
      for (int d = 0; d < 6; ++d) h += els[e][d] * w1s[d * 64 + c];
      s += h; s2 += h * h;
    }
  }
  red[grp][c] = s;
  __syncthreads();
  red[4 + grp][c] = s2;
  __syncthreads();
  if (tid < 64) {
    float S = red[0][tid] + red[1][tid] + red[2][tid] + red[3][tid];
    float Q = red[4][tid] + red[5][tid] + red[6][tid] + red[7][tid];
    psum[bid * 64 + tid] = S;
    psq[bid * 64 + tid] = Q;
  }
}

__global__ void bn_finalize_kernel(const float* __restrict__ psum, const float* __restrict__ psq,
                                   const float* __restrict__ gamma, const float* __restrict__ beta,
                                   float* __restrict__ bns, float* __restrict__ bnh) {
  int c = threadIdx.x;   // 64 threads
  float s = 0.f, q = 0.f;
  for (int b = 0; b < 512; ++b) { s += psum[b * 64 + c]; q += psq[b * 64 + c]; }
  const float inv = 1.0f / 655360.0f;
  float mu = s * inv;
  float var = q * inv - mu * mu;
  float sc = gamma[c] * rsqrtf(var + 1e-5f);
  bns[c] = sc;
  bnh[c] = beta[c] - mu * sc;
}

// ---------------- edge MLP via split-f16 MFMA (fp32-accurate) ----------------
// Block = 4 points -> 80 edge rows. A = h (hi+lo f16), B = W2 (hi+lo f16),
// out = Ah*Bh + Ah*Bl + Al*Bh (lo*lo dropped, rel err ~2e-7). Max over K=20 -> x1.
__global__ __launch_bounds__(256) void edge_mlp_kernel(
    const float* __restrict__ pos, const int* __restrict__ nbr,
    const float* __restrict__ W1, const float* __restrict__ b1v,
    const float* __restrict__ bns, const float* __restrict__ bnh,
    const float* __restrict__ W2, const float* __restrict__ b2v,
    float* __restrict__ x1) {
  __shared__ __align__(16) char elds[53248];
  _Float16* Ah = (_Float16*)(elds);            // [80][64] swizzled, 10240 B
  _Float16* Al = (_Float16*)(elds + 10240);    // 10240 B
  _Float16* Bh = (_Float16*)(elds + 20480);    // [128 cols][64] swizzled, 16384 B
  _Float16* Bl = (_Float16*)(elds + 36864);    // 16384 B
  float* outb = (float*)elds;                  // [80][129] fp32, reused after MFMA
  __shared__ float w1s[384];
  __shared__ float b1s[64], scs[64], shs[64];
  int tid = threadIdx.x, bid = blockIdx.x;
  for (int f = tid; f < 384; f += 256) w1s[f] = W1[f];
  if (tid < 64) { b1s[tid] = b1v[tid]; scs[tid] = bns[tid]; shs[tid] = bnh[tid]; }
  // stage W2 -> Bh/Bl (coalesced global read, scattered 2B LDS writes; one-time)
#pragma unroll
  for (int i = 0; i < 32; ++i) {
    int flat = tid + 256 * i;        // d = flat>>7 (0..63), c = flat&127
    int dd = flat >> 7, c = flat & 127;
    float v = W2[flat];
    _Float16 hi = (_Float16)v;
    _Float16 lo = (_Float16)(v - (float)hi);
    int byte = c * 128 + ((((dd >> 3) ^ (c & 7))) << 4) + (dd & 7) * 2;
    *(_Float16*)((char*)Bh + byte) = hi;
    *(_Float16*)((char*)Bl + byte) = lo;
  }
  __syncthreads();
  // h-gen: h[80][64] -> Ah/Al
#pragma unroll
  for (int m = 0; m < 20; ++m) {
    int flat = tid + 256 * m;
    int row = flat >> 6;            // 0..79
    int d = flat & 63;
    int j = nbr[bid * 80 + row];
    int P = bid * 4 + (row / 20);
    float pix = pos[3 * P], piy = pos[3 * P + 1], piz = pos[3 * P + 2];
    float e3 = pos[3 * j] - pix, e4 = pos[3 * j + 1] - piy, e5 = pos[3 * j + 2] - piz;
    float h = b1s[d];
    h += pix * w1s[d] + piy * w1s[64 + d] + piz * w1s[128 + d]
       + e3 * w1s[192 + d] + e4 * w1s[256 + d] + e5 * w1s[320 + d];
    h = scs[d] * h + shs[d];
    h = fmaxf(h, 0.f);
    _Float16 hi = (_Float16)h;
    _Float16 lo = (_Float16)(h - (float)hi);
    int byte = row * 128 + ((((d >> 3) ^ (row & 7))) << 4) + (d & 7) * 2;
    *(_Float16*)((char*)Ah + byte) = hi;
    *(_Float16*)((char*)Al + byte) = lo;
  }
  __syncthreads();
  int wave = tid >> 6, lane = tid & 63;
  int l15 = lane & 15, l4 = lane >> 4;
  f32x4 acc[5][2] = {};
#pragma unroll
  for (int ks = 0; ks < 2; ++ks) {
    int slotk = ks * 4 + l4;
    half8 bfh[2], bfl[2];
#pragma unroll
    for (int ci = 0; ci < 2; ++ci) {
      int col = (wave * 2 + ci) * 16 + l15;
      int byte = col * 128 + ((slotk ^ (col & 7)) << 4);
      bfh[ci] = *(const half8*)((char*)Bh + byte);
      bfl[ci] = *(const half8*)((char*)Bl + byte);
    }
#pragma unroll
    for (int rt = 0; rt < 5; ++rt) {
      int row = rt * 16 + l15;
      int byte = row * 128 + ((slotk ^ (row & 7)) << 4);
      half8 ah = *(const half8*)((char*)Ah + byte);
      half8 al = *(const half8*)((char*)Al + byte);
#pragma unroll
      for (int ci = 0; ci < 2; ++ci) {
        acc[rt][ci] = __builtin_amdgcn_mfma_f32_16x16x32_f16(ah, bfh[ci], acc[rt][ci], 0, 0, 0);
        acc[rt][ci] = __builtin_amdgcn_mfma_f32_16x16x32_f16(ah, bfl[ci], acc[rt][ci], 0, 0, 0);
        acc[rt][ci] = __builtin_amdgcn_mfma_f32_16x16x32_f16(al, bfh[ci], acc[rt][ci], 0, 0, 0);
      }
    }
  }
  __syncthreads();   // A/B reads done -> outb may overwrite
#pragma unroll
  for (int rt = 0; rt < 5; ++rt)
#pragma unroll
    for (int ci = 0; ci < 2; ++ci) {
      int col = (wave * 2 + ci) * 16 + l15;
#pragma unroll
      for (int q = 0; q < 4; ++q) {
        int row = rt * 16 + l4 * 4 + q;
        outb[row * 129 + col] = acc[rt][ci][q];
      }
    }
  __syncthreads();
#pragma unroll
  for (int r = 0; r < 2; ++r) {
    int it = tid + 256 * r;          // 512 items: p = it>>7, c = it&127
    int p = it >> 7, c = it & 127;
    float mx = -1e30f;
#pragma unroll
    for (int e = 0; e < 20; ++e) mx = fmaxf(mx, outb[(p * 20 + e) * 129 + c]);
    x1[((size_t)bid * 4 + p) * 128 + c] = mx + b2v[c];
  }
}

// ---------------- KAN1 tables (padded to 2944): j -> (input dim, window*k) ----------------
__global__ void kan1_tables_kernel(int* __restrict__ dimt, float* __restrict__ wkt) {
  int j = blockIdx.x * 256 + threadIdx.x;
  if (j >= 2944) return;
  if (j >= 2912) { dimt[j] = 0; wkt[j] = 0.0f; return; }
  int r = j % 1456;
  int n = r / 364, r2 = r % 364;
  int w = r2 / 7, g = r2 % 7;
  dimt[j] = n * 20 + w;
  float bart = 1.0f - fabsf(2.0f * (float)w / 52.0f - 1.0f);
  wkt[j] = bart * (float)(g + 1);
}

// ---------------- c1 [2,1024,4,52,7] -> Cf16 [1024][2944] (o-major, zero pad) ----------------
__global__ void c1_to_f16_kernel(const float* __restrict__ c1, _Float16* __restrict__ Cf) {
  int L = blockIdx.x * 256 + threadIdx.x;
  if (L >= 1024 * 2944) return;
  int o = L / 2944, j = L % 2944;
  float v = 0.0f;
  if (j < 2912) {
    int t = j / 1456, r = j % 1456;
    v = c1[(size_t)(t * 1024 + o) * 1456 + r];
  }
  Cf[L] = (_Float16)v;
}

// ---------------- KAN1 MFMA GEMM [32768,2944]x[2944,1024], A = trig on the fly ----------------
// BM=128 BN=128 BK=64, 256 thr (4 waves 2x2), wave tile 64x64 (4x4 16x16x32 frags).
// Small block -> 3-4 independent blocks/CU for barrier overlap.
__global__ __launch_bounds__(256, 4) void kan1_gemm_kernel(
    const float* __restrict__ x1, const _Float16* __restrict__ Cf,
    const int* __restrict__ dimt, const float* __restrict__ wkt,
    float* __restrict__ pmax, float* __restrict__ psump) {
  __shared__ __align__(16) _Float16 Asm[128 * 64];   // swizzled row-major [row][k-slot^]
  __shared__ __align__(16) _Float16 Bsm[128 * 64];   // swizzled col-major [col][k-slot^]
  __shared__ int   tdim[2][64];
  __shared__ float twk[2][64];
  int tid = threadIdx.x;
  int bm = blockIdx.x, bn = blockIdx.y;
  int m0 = bm << 7, n0 = bn << 7;
  int wave = tid >> 6, lane = tid & 63;
  int wr = wave >> 1, wc = wave & 1;
  int l15 = lane & 15, l4 = lane >> 4;

  if (tid < 64) { tdim[0][tid] = dimt[tid]; twk[0][tid] = wkt[tid]; }
  f32x4 acc[4][4] = {};
  __syncthreads();

  for (int t = 0; t < 46; ++t) {
    int j0 = t << 6;
    // ---- stage B tile via global_load_lds (linear LDS dest, pre-swizzled source) ----
#pragma unroll
    for (int i = 0; i < 4; ++i) {
      int idx = i * 256 + tid;          // 0..1023 : col = idx>>3, slot = idx&7
      int col = idx >> 3, slot = idx & 7;
      int sslot = slot ^ (col & 7);
      const _Float16* src = Cf + (size_t)(n0 + col) * 2944 + j0 + sslot * 8;
      gload16(src, (char*)Bsm + idx * 16);
    }
    if (t < 45 && tid < 64) {
      tdim[(t + 1) & 1][tid] = dimt[j0 + 64 + tid];
      twk[(t + 1) & 1][tid] = wkt[j0 + 64 + tid];
    }
    // ---- A-gen: cos(x*wk - phase) -> swizzled LDS ----
    const int* td = tdim[t & 1];
    const float* tw = twk[t & 1];
#pragma unroll
    for (int rep = 0; rep < 4; ++rep) {
      int slot = tid + rep * 256;       // 0..1023 : r = slot>>3, s = slot&7
      int r = slot >> 3, s = slot & 7;
      const float* xrow = x1 + (size_t)(m0 + r) * 128;
      int d0 = td[s * 8], d7 = td[s * 8 + 7];
      float x0 = xrow[d0], x7 = xrow[d7];
      half8 av;
#pragma unroll
      for (int e = 0; e < 8; ++e) {
        int jj = s * 8 + e;
        float xv = (td[jj] == d0) ? x0 : x7;
        float ph = (j0 + jj >= 1456) ? 1.57079632679489662f : 0.0f;
        av[e] = (_Float16)__cosf(xv * tw[jj] - ph);
      }
      *(half8*)((char*)Asm + r * 128 + ((s ^ (r & 7)) << 4)) = av;
    }
    __syncthreads();
    // ---- MFMA ----
#pragma unroll
    for (int ksub = 0; ksub < 2; ++ksub) {
      int slotk = ksub * 4 + l4;
      half8 bf[4];
#pragma unroll
      for (int ni = 0; ni < 4; ++ni) {
        int col = wc * 64 + ni * 16 + l15;
        bf[ni] = *(const half8*)((char*)Bsm + col * 128 + ((slotk ^ (col & 7)) << 4));
      }
#pragma unroll
      for (int mi = 0; mi < 4; ++mi) {
        int row = wr * 64 + mi * 16 + l15;
        half8 af = *(const half8*)((char*)Asm + row * 128 + ((slotk ^ (row & 7)) << 4));
#pragma unroll
        for (int ni = 0; ni < 4; ++ni)
          acc[mi][ni] = __builtin_amdgcn_mfma_f32_16x16x32_f16(af, bf[ni], acc[mi][ni], 0, 0, 0);
      }
    }
    __syncthreads();
  }

  // ---- fused pooling epilogue: max/sum over 128 rows (reuse Bsm as scratch) ----
  float* pooled = (float*)Bsm;           // [2][2][128]
#pragma unroll
  for (int ni = 0; ni < 4; ++ni) {
    float mx = -1e30f, sm = 0.f;
#pragma unroll
    for (int mi = 0; mi < 4; ++mi)
#pragma unroll
      for (int q = 0; q < 4; ++q) {
        float v = acc[mi][ni][q];
        mx = fmaxf(mx, v); sm += v;
      }
    mx = fmaxf(mx, __shfl_xor(mx, 16)); sm += __shfl_xor(sm, 16);
    mx = fmaxf(mx, __shfl_xor(mx, 32)); sm += __shfl_xor(sm, 32);
    if (l4 == 0) {
      int col = wc * 64 + ni * 16 + l15;
      pooled[(wr * 2 + 0) * 128 + col] = mx;
      pooled[(wr * 2 + 1) * 128 + col] = sm;
    }
  }
  __syncthreads();
  if (tid < 128) {
    float mx = fmaxf(pooled[tid], pooled[2 * 128 + tid]);
    float sm = pooled[128 + tid] + pooled[3 * 128 + tid];
    pmax[(size_t)bm * 1024 + n0 + tid] = mx;
    psump[(size_t)bm * 1024 + n0 + tid] = sm;
  }
}

// ---------------- final pool: 8 m-block partials -> gmax/gmean (+bi1) ----------------
__global__ void pool_reduce_kernel(const float* __restrict__ pmax, const float* __restrict__ psump,
                                   const float* __restrict__ bi1,
                                   float* __restrict__ gmax, float* __restrict__ gmean) {
  int gid = blockIdx.x * 256 + threadIdx.x;   // 32768 = 32 graphs x 1024 cols
  int b = gid >> 10, col = gid & 1023;
  float mx = -1e30f, sm = 0.f;
  for (int t = 0; t < 8; ++t) {
    mx = fmaxf(mx, pmax[(size_t)(b * 8 + t) * 1024 + col]);
    sm += psump[(size_t)(b * 8 + t) * 1024 + col];
  }
  float bias = bi1[col];
  gmax[gid] = mx + bias;
  gmean[gid] = sm * (1.0f / 1024.0f) + bias;
}

// ---------------- STFT-KAN2 partials: xcat [32,2048] -> part [32,16,7] ----------------
__global__ __launch_bounds__(256) void kan2_kernel(
    const float* __restrict__ gmax, const float* __restrict__ gmean,
    const float* __restrict__ c2, float* __restrict__ part) {
  __shared__ float xc[2048];
  __shared__ float hw[197];
  __shared__ float racc[7][256];
  int b = blockIdx.x, s = blockIdx.y, tid = threadIdx.x;
  for (int f = tid; f < 1024; f += 256) {
    xc[f] = gmax[b * 1024 + f];
    xc[1024 + f] = gmean[b * 1024 + f];
  }
  for (int f = tid; f < 197; f += 256)
    hw[f] = 0.5f * (1.0f - cosf(6.283185307179586f * (float)f / 197.0f));
  float acc[7] = {};
  __syncthreads();
  int qlo = (52205 * s) / 16, qhi = (52205 * (s + 1)) / 16;
  for (int q = qlo + tid; q < qhi; q += 256) {
    int n = q / 197;
    int w = q - n * 197;
    float xw = xc[n * 7 + w] * hw[w];
    float s1, c1v;
    __sincosf(xw, &s1, &c1v);
    float ckv[6], skv[6];
    {
      float ck = c1v, sk = s1;
#pragma unroll
      for (int g = 0; g < 6; ++g) {
        ckv[g] = ck; skv[g] = sk;
        float cn = ck * c1v - sk * s1;
        sk = sk * c1v + ck * s1;
        ck = cn;
      }
    }
    int base = q * 6;
#pragma unroll
    for (int o = 0; o < 7; ++o) {
      const float* pc = c2 + (size_t)o * 313230 + base;
      const float* ps = c2 + (size_t)(o + 7) * 313230 + base;
      float sc = 0.f, ss = 0.f;
#pragma unroll
      for (int g = 0; g < 6; ++g) { sc += ckv[g] * pc[g]; ss += skv[g] * ps[g]; }
      acc[o] += sc + ss;
    }
  }
#pragma unroll
  for (int o = 0; o < 7; ++o) racc[o][tid] = acc[o];
  __syncthreads();
  for (int st = 128; st >= 1; st >>= 1) {
    if (tid < st)
#pragma unroll
      for (int o = 0; o < 7; ++o) racc[o][tid] += racc[o][tid + st];
    __syncthreads();
  }
  if (tid < 7) part[(b * 16 + s) * 7 + tid] = racc[tid][0];
}

__global__ void kan2_reduce_kernel(const float* __restrict__ part, const float* __restrict__ bi2,
                                   float* __restrict__ out) {
  int i = threadIdx.x;   // 224 threads: (b, o)
  if (i >= 224) return;
  int b = i / 7, o = i % 7;
  float s = 0.f;
  for (int t = 0; t < 16; ++t) s += part[(b * 16 + t) * 7 + o];
  out[b * 7 + o] = s + bi2[o];
}

// ---------------------------------------------------------------------------
extern "C" void kernel_launch(void* const* d_in, const int* in_sizes, int n_in,
                              void* d_out, int out_size, void* d_ws, size_t ws_size,
                              hipStream_t stream) {
  const float* pos    = (const float*)d_in[0];
  const float* W1     = (const float*)d_in[2];
  const float* b1     = (const float*)d_in[3];
  const float* gamma1 = (const float*)d_in[4];
  const float* beta1  = (const float*)d_in[5];
  const float* W2     = (const float*)d_in[6];
  const float* b2     = (const float*)d_in[7];
  const float* c1     = (const float*)d_in[8];
  const float* bi1    = (const float*)d_in[9];
  const float* c2     = (const float*)d_in[10];
  const float* bi2    = (const float*)d_in[11];
  float* out = (float*)d_out;
  char* ws = (char*)d_ws;

  int*      nbr   = (int*)     (ws + 0);          // 2,621,440
  float*    x1    = (float*)   (ws + 2621440);    // 16,777,216
  _Float16* Cf    = (_Float16*)(ws + 19398656);   // 6,029,312
  int*      dimt  = (int*)     (ws + 25427968);   // 11,776
  float*    wkt   = (float*)   (ws + 25439744);   // 11,776
  float*    psum  = (float*)   (ws + 25451520);   // 131,072
  float*    psq   = (float*)   (ws + 25582592);   // 131,072
  float*    bns   = (float*)   (ws + 25713664);   // 256
  float*    bnh   = (float*)   (ws + 25713920);   // 256
  float*    pmax  = (float*)   (ws + 25714176);   // 1,048,576
  float*    psump = (float*)   (ws + 26762752);   // 1,048,576
  float*    gmax  = (float*)   (ws + 27811328);   // 131,072
  float*    gmean = (float*)   (ws + 27942400);   // 131,072
  float*    part  = (float*)   (ws + 28073472);   // 14,336
  if (ws_size < 28087808) return;

  knn_kernel<<<8192, 256, 0, stream>>>(pos, nbr);
  kan1_tables_kernel<<<12, 256, 0, stream>>>(dimt, wkt);
  c1_to_f16_kernel<<<11776, 256, 0, stream>>>(c1, Cf);
  edge_stats_kernel<<<512, 256, 0, stream>>>(pos, nbr, W1, b1, psum, psq);
  bn_finalize_kernel<<<1, 64, 0, stream>>>(psum, psq, gamma1, beta1, bns, bnh);
  edge_mlp_kernel<<<8192, 256, 0, stream>>>(pos, nbr, W1, b1, bns, bnh, W2, b2, x1);
  kan1_gemm_kernel<<<dim3(256, 8), 256, 0, stream>>>(x1, Cf, dimt, wkt, pmax, psump);
  pool_reduce_kernel<<<128, 256, 0, stream>>>(pmax, psump, bi1, gmax, gmean);
  kan2_kernel<<<dim3(32, 16), 256, 0, stream>>>(gmax, gmean, c2, part);
  kan2_reduce_kernel<<<1, 256, 0, stream>>>(part, bi2, out);
}

// Round 5
// 601.473 us; speedup vs baseline: 6.6474x; 1.0986x over previous
//
#include <hip/hip_runtime.h>
#include <cstdint>

typedef _Float16 half8 __attribute__((ext_vector_type(8)));
typedef float f32x4 __attribute__((ext_vector_type(4)));

__device__ __forceinline__ void gload16(const void* g, void* l) {
  __builtin_amdgcn_global_load_lds(
      (const __attribute__((address_space(1))) void*)g,
      (__attribute__((address_space(3))) void*)l, 16, 0, 0);
}

// ---------------- kNN: one WAVE per query point, barrier-free selection ----------------
__global__ __launch_bounds__(256) void knn_kernel(const float* __restrict__ pos,
                                                  int* __restrict__ nbr) {
  __shared__ float px[1024], py[1024], pz[1024], sq[1024];
  int tid = threadIdx.x;
  int b = blockIdx.x >> 8;                 // graph id (256 blocks per graph)
  const float* pg = pos + (size_t)b * 3072;
  for (int m = 0; m < 4; ++m) {
    int j = m * 256 + tid;
    float x = pg[3 * j], y = pg[3 * j + 1], z = pg[3 * j + 2];
    px[j] = x; py[j] = y; pz[j] = z; sq[j] = x * x + y * y + z * z;
  }
  __syncthreads();
  int wave = tid >> 6, lane = tid & 63;
  int n = (blockIdx.x & 255) * 4 + wave;   // local query index in graph
  float xi = px[n], yi = py[n], zi = pz[n], si = sq[n];
  float d[16];
#pragma unroll
  for (int i = 0; i < 16; ++i) {
    int j = i * 64 + lane;
    float dd = si + sq[j] - 2.0f * (xi * px[j] + yi * py[j] + zi * pz[j]);
    d[i] = (j == n) ? 1e30f : dd;          // exclude self
  }
  int outbase = (b * 1024 + n) * 20;
  for (int kk = 0; kk < 20; ++kk) {
    float lmin = d[0]; int lpos = 0;
#pragma unroll
    for (int i = 1; i < 16; ++i)
      if (d[i] < lmin) { lmin = d[i]; lpos = i; }
    float bv = lmin; int bi = lpos * 64 + lane;
#pragma unroll
    for (int off = 1; off < 64; off <<= 1) {
      float ov = __shfl_xor(bv, off);
      int   oi = __shfl_xor(bi, off);
      if (ov < bv || (ov == bv && oi < bi)) { bv = ov; bi = oi; }
    }
    if (lane == 0) nbr[outbase + kk] = b * 1024 + bi;
    if ((bi & 63) == lane) {
      int rp = bi >> 6;
#pragma unroll
      for (int i = 0; i < 16; ++i)
        if (i == rp) d[i] = 1e30f;
    }
  }
}

// ---------------- edge MLP layer1 stats (sum, sumsq per channel) ----------------
__global__ __launch_bounds__(256) void edge_stats_kernel(
    const float* __restrict__ pos, const int* __restrict__ nbr,
    const float* __restrict__ W1, const float* __restrict__ b1v,
    float* __restrict__ psum, float* __restrict__ psq) {
  __shared__ float els[256][6];
  __shared__ float w1s[384];
  __shared__ float b1s[64];
  __shared__ float red[8][64];
  int tid = threadIdx.x, bid = blockIdx.x;
  for (int f = tid; f < 384; f += 256) w1s[f] = W1[f];
  if (tid < 64) b1s[tid] = b1v[tid];
  int c = tid & 63, grp = tid >> 6;
  float s = 0.f, s2 = 0.f;
  for (int ch = 0; ch < 5; ++ch) {
    int E = bid * 1280 + ch * 256 + tid;
    int p = E / 20;
    int j = nbr[E];
    float pix = pos[3 * p], piy = pos[3 * p + 1], piz = pos[3 * p + 2];
    float e3 = pos[3 * j] - pix, e4 = pos[3 * j + 1] - piy, e5 = pos[3 * j + 2] - piz;
    __syncthreads();
    els[tid][0] = pix; els[tid][1] = piy; els[tid][2] = piz;
    els[tid][3] = e3;  els[tid][4] = e4;  els[tid][5] = e5;
    __syncthreads();
    for (int m = 0; m < 64; ++m) {
      int e = grp * 64 + m;
      float h = b1s[c];
#pragma unroll
      for (int d = 0; d < 6; ++d) h += els[e][d] * w1s[d * 64 + c];
      s += h; s2 += h * h;
    }
  }
  red[grp][c] = s;
  __syncthreads();
  red[4 + grp][c] = s2;
  __syncthreads();
  if (tid < 64) {
    float S = red[0][tid] + red[1][tid] + red[2][tid] + red[3][tid];
    float Q = red[4][tid] + red[5][tid] + red[6][tid] + red[7][tid];
    psum[bid * 64 + tid] = S;
    psq[bid * 64 + tid] = Q;
  }
}

__global__ void bn_finalize_kernel(const float* __restrict__ psum, const float* __restrict__ psq,
                                   const float* __restrict__ gamma, const float* __restrict__ beta,
                                   float* __restrict__ bns, float* __restrict__ bnh) {
  int c = threadIdx.x;   // 64 threads
  float s = 0.f, q = 0.f;
  for (int b = 0; b < 512; ++b) { s += psum[b * 64 + c]; q += psq[b * 64 + c]; }
  const float inv = 1.0f / 655360.0f;
  float mu = s * inv;
  float var = q * inv - mu * mu;
  float sc = gamma[c] * rsqrtf(var + 1e-5f);
  bns[c] = sc;
  bnh[c] = beta[c] - mu * sc;
}

// ---------------- edge MLP via split-f16 MFMA (fp32-accurate) ----------------
__global__ __launch_bounds__(256) void edge_mlp_kernel(
    const float* __restrict__ pos, const int* __restrict__ nbr,
    const float* __restrict__ W1, const float* __restrict__ b1v,
    const float* __restrict__ bns, const float* __restrict__ bnh,
    const float* __restrict__ W2, const float* __restrict__ b2v,
    float* __restrict__ x1) {
  __shared__ __align__(16) char elds[53248];
  _Float16* Ah = (_Float16*)(elds);            // [80][64] swizzled, 10240 B
  _Float16* Al = (_Float16*)(elds + 10240);    // 10240 B
  _Float16* Bh = (_Float16*)(elds + 20480);    // [128 cols][64] swizzled, 16384 B
  _Float16* Bl = (_Float16*)(elds + 36864);    // 16384 B
  float* outb = (float*)elds;                  // [80][129] fp32, reused after MFMA
  __shared__ float w1s[384];
  __shared__ float b1s[64], scs[64], shs[64];
  int tid = threadIdx.x, bid = blockIdx.x;
  for (int f = tid; f < 384; f += 256) w1s[f] = W1[f];
  if (tid < 64) { b1s[tid] = b1v[tid]; scs[tid] = bns[tid]; shs[tid] = bnh[tid]; }
#pragma unroll
  for (int i = 0; i < 32; ++i) {
    int flat = tid + 256 * i;        // d = flat>>7 (0..63), c = flat&127
    int dd = flat >> 7, c = flat & 127;
    float v = W2[flat];
    _Float16 hi = (_Float16)v;
    _Float16 lo = (_Float16)(v - (float)hi);
    int byte = c * 128 + ((((dd >> 3) ^ (c & 7))) << 4) + (dd & 7) * 2;
    *(_Float16*)((char*)Bh + byte) = hi;
    *(_Float16*)((char*)Bl + byte) = lo;
  }
  __syncthreads();
#pragma unroll
  for (int m = 0; m < 20; ++m) {
    int flat = tid + 256 * m;
    int row = flat >> 6;            // 0..79
    int d = flat & 63;
    int j = nbr[bid * 80 + row];
    int P = bid * 4 + (row / 20);
    float pix = pos[3 * P], piy = pos[3 * P + 1], piz = pos[3 * P + 2];
    float e3 = pos[3 * j] - pix, e4 = pos[3 * j + 1] - piy, e5 = pos[3 * j + 2] - piz;
    float h = b1s[d];
    h += pix * w1s[d] + piy * w1s[64 + d] + piz * w1s[128 + d]
       + e3 * w1s[192 + d] + e4 * w1s[256 + d] + e5 * w1s[320 + d];
    h = scs[d] * h + shs[d];
    h = fmaxf(h, 0.f);
    _Float16 hi = (_Float16)h;
    _Float16 lo = (_Float16)(h - (float)hi);
    int byte = row * 128 + ((((d >> 3) ^ (row & 7))) << 4) + (d & 7) * 2;
    *(_Float16*)((char*)Ah + byte) = hi;
    *(_Float16*)((char*)Al + byte) = lo;
  }
  __syncthreads();
  int wave = tid >> 6, lane = tid & 63;
  int l15 = lane & 15, l4 = lane >> 4;
  f32x4 acc[5][2] = {};
#pragma unroll
  for (int ks = 0; ks < 2; ++ks) {
    int slotk = ks * 4 + l4;
    half8 bfh[2], bfl[2];
#pragma unroll
    for (int ci = 0; ci < 2; ++ci) {
      int col = (wave * 2 + ci) * 16 + l15;
      int byte = col * 128 + ((slotk ^ (col & 7)) << 4);
      bfh[ci] = *(const half8*)((char*)Bh + byte);
      bfl[ci] = *(const half8*)((char*)Bl + byte);
    }
#pragma unroll
    for (int rt = 0; rt < 5; ++rt) {
      int row = rt * 16 + l15;
      int byte = row * 128 + ((slotk ^ (row & 7)) << 4);
      half8 ah = *(const half8*)((char*)Ah + byte);
      half8 al = *(const half8*)((char*)Al + byte);
#pragma unroll
      for (int ci = 0; ci < 2; ++ci) {
        acc[rt][ci] = __builtin_amdgcn_mfma_f32_16x16x32_f16(ah, bfh[ci], acc[rt][ci], 0, 0, 0);
        acc[rt][ci] = __builtin_amdgcn_mfma_f32_16x16x32_f16(ah, bfl[ci], acc[rt][ci], 0, 0, 0);
        acc[rt][ci] = __builtin_amdgcn_mfma_f32_16x16x32_f16(al, bfh[ci], acc[rt][ci], 0, 0, 0);
      }
    }
  }
  __syncthreads();   // A/B reads done -> outb may overwrite
#pragma unroll
  for (int rt = 0; rt < 5; ++rt)
#pragma unroll
    for (int ci = 0; ci < 2; ++ci) {
      int col = (wave * 2 + ci) * 16 + l15;
#pragma unroll
      for (int q = 0; q < 4; ++q) {
        int row = rt * 16 + l4 * 4 + q;
        outb[row * 129 + col] = acc[rt][ci][q];
      }
    }
  __syncthreads();
#pragma unroll
  for (int r = 0; r < 2; ++r) {
    int it = tid + 256 * r;          // 512 items: p = it>>7, c = it&127
    int p = it >> 7, c = it & 127;
    float mx = -1e30f;
#pragma unroll
    for (int e = 0; e < 20; ++e) mx = fmaxf(mx, outb[(p * 20 + e) * 129 + c]);
    x1[((size_t)bid * 4 + p) * 128 + c] = mx + b2v[c];
  }
}

// ---------------- KAN1 tables (padded to 2944): j -> (input dim, window*k) ----------------
__global__ void kan1_tables_kernel(int* __restrict__ dimt, float* __restrict__ wkt) {
  int j = blockIdx.x * 256 + threadIdx.x;
  if (j >= 2944) return;
  if (j >= 2912) { dimt[j] = 0; wkt[j] = 0.0f; return; }
  int r = j % 1456;
  int n = r / 364, r2 = r % 364;
  int w = r2 / 7, g = r2 % 7;
  dimt[j] = n * 20 + w;
  float bart = 1.0f - fabsf(2.0f * (float)w / 52.0f - 1.0f);
  wkt[j] = bart * (float)(g + 1);
}

// ---------------- c1 [2,1024,4,52,7] -> Cf16 [1024][2944] (o-major, zero pad) ----------------
__global__ void c1_to_f16_kernel(const float* __restrict__ c1, _Float16* __restrict__ Cf) {
  int L = blockIdx.x * 256 + threadIdx.x;
  if (L >= 1024 * 2944) return;
  int o = L / 2944, j = L % 2944;
  float v = 0.0f;
  if (j < 2912) {
    int t = j / 1456, r = j % 1456;
    v = c1[(size_t)(t * 1024 + o) * 1456 + r];
  }
  Cf[L] = (_Float16)v;
}

// ---------------- KAN1 MFMA GEMM [32768,2944]x[2944,1024], A = trig on the fly ----------------
// BM=128 BN=256 BK=64, 512 thr (8 waves 2x4), wave tile 64x64.
// 2-phase double-buffered pipeline: MFMA(t) overlaps trig-gen(t+1) + B-stage(t+1).
__global__ __launch_bounds__(512, 2) void kan1_gemm_kernel(
    const float* __restrict__ x1, const _Float16* __restrict__ Cf,
    const int* __restrict__ dimt, const float* __restrict__ wkt,
    float* __restrict__ pmax, float* __restrict__ psump) {
  __shared__ __align__(16) _Float16 Asm[2][128 * 64];   // 2 x 16 KB, swizzled
  __shared__ __align__(16) _Float16 Bsm[2][256 * 64];   // 2 x 32 KB, swizzled
  __shared__ int   tdim[2][64];
  __shared__ float twk[2][64];
  int tid = threadIdx.x;
  int bm = blockIdx.x, bn = blockIdx.y;
  int m0 = bm << 7, n0 = bn << 8;
  int wave = tid >> 6, lane = tid & 63;
  int wr = wave >> 2, wc = wave & 3;        // 2 x 4 wave grid
  int l15 = lane & 15, l4 = lane >> 4;

  auto stageB = [&](int t, int nb) {
    int j0 = t << 6;
#pragma unroll
    for (int i = 0; i < 4; ++i) {
      int idx = i * 512 + tid;          // 0..2047 : col = idx>>3, slot = idx&7
      int col = idx >> 3, slot = idx & 7;
      int sslot = slot ^ (col & 7);
      gload16(Cf + (size_t)(n0 + col) * 2944 + j0 + sslot * 8,
              (char*)Bsm[nb] + idx * 16);
    }
  };
  auto agen = [&](int t, int nb) {
    const int* td = tdim[t & 1];
    const float* tw = twk[t & 1];
    int j0 = t << 6;
#pragma unroll
    for (int rep = 0; rep < 2; ++rep) {
      int slot = tid + rep * 512;       // 0..1023 : r = slot>>3, s = slot&7
      int r = slot >> 3, s = slot & 7;
      const float* xrow = x1 + (size_t)(m0 + r) * 128;
      int d0 = td[s * 8], d7 = td[s * 8 + 7];
      float x0 = xrow[d0], x7 = xrow[d7];
      half8 av;
#pragma unroll
      for (int e = 0; e < 8; ++e) {
        int jj = s * 8 + e;
        float xv = (td[jj] == d0) ? x0 : x7;
        float ph = (j0 + jj >= 1456) ? 1.57079632679489662f : 0.0f;
        av[e] = (_Float16)__cosf(xv * tw[jj] - ph);
      }
      *(half8*)((char*)Asm[nb] + r * 128 + ((s ^ (r & 7)) << 4)) = av;
    }
  };

  // prologue: tables for t=0,1; stage tile 0
  if (tid < 64)                { tdim[0][tid]      = dimt[tid];            twk[0][tid]      = wkt[tid]; }
  else if (tid < 128)          { tdim[1][tid - 64] = dimt[tid];            twk[1][tid - 64] = wkt[tid]; }
  f32x4 acc[4][4] = {};
  __syncthreads();
  stageB(0, 0);
  agen(0, 0);
  __syncthreads();   // drains vmcnt + lgkmcnt

  for (int t = 0; t < 46; ++t) {
    int cur = t & 1, nxt = cur ^ 1;
    // 1) issue next B-tile loads early (latency hidden under gen+MFMA)
    if (t < 45) stageB(t + 1, nxt);
    // 2) read this tile's MFMA operands into registers
    half8 af[2][4], bf[2][4];
#pragma unroll
    for (int ksub = 0; ksub < 2; ++ksub) {
      int slotk = ksub * 4 + l4;
#pragma unroll
      for (int mi = 0; mi < 4; ++mi) {
        int row = wr * 64 + mi * 16 + l15;
        af[ksub][mi] = *(const half8*)((char*)Asm[cur] + row * 128 + ((slotk ^ (row & 7)) << 4));
      }
#pragma unroll
      for (int ni = 0; ni < 4; ++ni) {
        int col = wc * 64 + ni * 16 + l15;
        bf[ksub][ni] = *(const half8*)((char*)Bsm[cur] + col * 128 + ((slotk ^ (col & 7)) << 4));
      }
    }
    // 3) generate next A-tile (VALU) — independent of the register MFMAs below
    if (t < 45) agen(t + 1, nxt);
    if (t < 44 && tid < 64) {
      tdim[cur][tid] = dimt[(t + 2) * 64 + tid];
      twk[cur][tid]  = wkt[(t + 2) * 64 + tid];
    }
    // 4) MFMA on current tile (register-only; overlaps step 3's VALU)
#pragma unroll
    for (int ksub = 0; ksub < 2; ++ksub)
#pragma unroll
      for (int mi = 0; mi < 4; ++mi)
#pragma unroll
        for (int ni = 0; ni < 4; ++ni)
          acc[mi][ni] = __builtin_amdgcn_mfma_f32_16x16x32_f16(af[ksub][mi], bf[ksub][ni], acc[mi][ni], 0, 0, 0);
    __syncthreads();
  }

  // ---- fused pooling epilogue: max/sum over the block's 128 rows ----
  float* pooled = (float*)Asm;           // [wr][max|sum][256], 4 KB (safe after last barrier)
#pragma unroll
  for (int ni = 0; ni < 4; ++ni) {
    float mx = -1e30f, sm = 0.f;
#pragma unroll
    for (int mi = 0; mi < 4; ++mi)
#pragma unroll
      for (int q = 0; q < 4; ++q) {
        float v = acc[mi][ni][q];
        mx = fmaxf(mx, v); sm += v;
      }
    mx = fmaxf(mx, __shfl_xor(mx, 16)); sm += __shfl_xor(sm, 16);
    mx = fmaxf(mx, __shfl_xor(mx, 32)); sm += __shfl_xor(sm, 32);
    if (l4 == 0) {
      int col = wc * 64 + ni * 16 + l15;
      pooled[(wr * 2 + 0) * 256 + col] = mx;
      pooled[(wr * 2 + 1) * 256 + col] = sm;
    }
  }
  __syncthreads();
  if (tid < 256) {
    float mx = fmaxf(pooled[tid], pooled[512 + tid]);
    float sm = pooled[256 + tid] + pooled[768 + tid];
    pmax[(size_t)bm * 1024 + n0 + tid] = mx;
    psump[(size_t)bm * 1024 + n0 + tid] = sm;
  }
}

// ---------------- final pool: 8 m-block partials -> gmax/gmean (+bi1) ----------------
__global__ void pool_reduce_kernel(const float* __restrict__ pmax, const float* __restrict__ psump,
                                   const float* __restrict__ bi1,
                                   float* __restrict__ gmax, float* __restrict__ gmean) {
  int gid = blockIdx.x * 256 + threadIdx.x;   // 32768 = 32 graphs x 1024 cols
  int b = gid >> 10, col = gid & 1023;
  float mx = -1e30f, sm = 0.f;
  for (int t = 0; t < 8; ++t) {
    mx = fmaxf(mx, pmax[(size_t)(b * 8 + t) * 1024 + col]);
    sm += psump[(size_t)(b * 8 + t) * 1024 + col];
  }
  float bias = bi1[col];
  gmax[gid] = mx + bias;
  gmean[gid] = sm * (1.0f / 1024.0f) + bias;
}

// ---------------- STFT-KAN2 partials: xcat [32,2048] -> part [32,16,7] ----------------
__global__ __launch_bounds__(256) void kan2_kernel(
    const float* __restrict__ gmax, const float* __restrict__ gmean,
    const float* __restrict__ c2, float* __restrict__ part) {
  __shared__ float xc[2048];
  __shared__ float hw[197];
  __shared__ float racc[7][256];
  int b = blockIdx.x, s = blockIdx.y, tid = threadIdx.x;
  for (int f = tid; f < 1024; f += 256) {
    xc[f] = gmax[b * 1024 + f];
    xc[1024 + f] = gmean[b * 1024 + f];
  }
  for (int f = tid; f < 197; f += 256)
    hw[f] = 0.5f * (1.0f - cosf(6.283185307179586f * (float)f / 197.0f));
  float acc[7] = {};
  __syncthreads();
  int qlo = (52205 * s) / 16, qhi = (52205 * (s + 1)) / 16;
  for (int q = qlo + tid; q < qhi; q += 256) {
    int n = q / 197;
    int w = q - n * 197;
    float xw = xc[n * 7 + w] * hw[w];
    float s1, c1v;
    __sincosf(xw, &s1, &c1v);
    float ckv[6], skv[6];
    {
      float ck = c1v, sk = s1;
#pragma unroll
      for (int g = 0; g < 6; ++g) {
        ckv[g] = ck; skv[g] = sk;
        float cn = ck * c1v - sk * s1;
        sk = sk * c1v + ck * s1;
        ck = cn;
      }
    }
    int base = q * 6;
#pragma unroll
    for (int o = 0; o < 7; ++o) {
      const float* pc = c2 + (size_t)o * 313230 + base;
      const float* ps = c2 + (size_t)(o + 7) * 313230 + base;
      float sc = 0.f, ss = 0.f;
#pragma unroll
      for (int g = 0; g < 6; ++g) { sc += ckv[g] * pc[g]; ss += skv[g] * ps[g]; }
      acc[o] += sc + ss;
    }
  }
#pragma unroll
  for (int o = 0; o < 7; ++o) racc[o][tid] = acc[o];
  __syncthreads();
  for (int st = 128; st >= 1; st >>= 1) {
    if (tid < st)
#pragma unroll
      for (int o = 0; o < 7; ++o) racc[o][tid] += racc[o][tid + st];
    __syncthreads();
  }
  if (tid < 7) part[(b * 16 + s) * 7 + tid] = racc[tid][0];
}

__global__ void kan2_reduce_kernel(const float* __restrict__ part, const float* __restrict__ bi2,
                                   float* __restrict__ out) {
  int i = threadIdx.x;   // 224 threads: (b, o)
  if (i >= 224) return;
  int b = i / 7, o = i % 7;
  float s = 0.f;
  for (int t = 0; t < 16; ++t) s += part[(b * 16 + t) * 7 + o];
  out[b * 7 + o] = s + bi2[o];
}

// ---------------------------------------------------------------------------
extern "C" void kernel_launch(void* const* d_in, const int* in_sizes, int n_in,
                              void* d_out, int out_size, void* d_ws, size_t ws_size,
                              hipStream_t stream) {
  const float* pos    = (const float*)d_in[0];
  const float* W1     = (const float*)d_in[2];
  const float* b1     = (const float*)d_in[3];
  const float* gamma1 = (const float*)d_in[4];
  const float* beta1  = (const float*)d_in[5];
  const float* W2     = (const float*)d_in[6];
  const float* b2     = (const float*)d_in[7];
  const float* c1     = (const float*)d_in[8];
  const float* bi1    = (const float*)d_in[9];
  const float* c2     = (const float*)d_in[10];
  const float* bi2    = (const float*)d_in[11];
  float* out = (float*)d_out;
  char* ws = (char*)d_ws;

  int*      nbr   = (int*)     (ws + 0);          // 2,621,440
  float*    x1    = (float*)   (ws + 2621440);    // 16,777,216
  _Float16* Cf    = (_Float16*)(ws + 19398656);   // 6,029,312
  int*      dimt  = (int*)     (ws + 25427968);   // 11,776
  float*    wkt   = (float*)   (ws + 25439744);   // 11,776
  float*    psum  = (float*)   (ws + 25451520);   // 131,072
  float*    psq   = (float*)   (ws + 25582592);   // 131,072
  float*    bns   = (float*)   (ws + 25713664);   // 256
  float*    bnh   = (float*)   (ws + 25713920);   // 256
  float*    pmax  = (float*)   (ws + 25714176);   // 1,048,576
  float*    psump = (float*)   (ws + 26762752);   // 1,048,576
  float*    gmax  = (float*)   (ws + 27811328);   // 131,072
  float*    gmean = (float*)   (ws + 27942400);   // 131,072
  float*    part  = (float*)   (ws + 28073472);   // 14,336
  if (ws_size < 28087808) return;

  knn_kernel<<<8192, 256, 0, stream>>>(pos, nbr);
  kan1_tables_kernel<<<12, 256, 0, stream>>>(dimt, wkt);
  c1_to_f16_kernel<<<11776, 256, 0, stream>>>(c1, Cf);
  edge_stats_kernel<<<512, 256, 0, stream>>>(pos, nbr, W1, b1, psum, psq);
  bn_finalize_kernel<<<1, 64, 0, stream>>>(psum, psq, gamma1, beta1, bns, bnh);
  edge_mlp_kernel<<<8192, 256, 0, stream>>>(pos, nbr, W1, b1, bns, bnh, W2, b2, x1);
  kan1_gemm_kernel<<<dim3(256, 4), 512, 0, stream>>>(x1, Cf, dimt, wkt, pmax, psump);
  pool_reduce_kernel<<<128, 256, 0, stream>>>(pmax, psump, bi1, gmax, gmean);
  kan2_kernel<<<dim3(32, 16), 256, 0, stream>>>(gmax, gmean, c2, part);
  kan2_reduce_kernel<<<1, 256, 0, stream>>>(part, bi2, out);
}

// Round 6
// 592.915 us; speedup vs baseline: 6.7433x; 1.0144x over previous
//
#include <hip/hip_runtime.h>
#include <cstdint>

typedef _Float16 half8 __attribute__((ext_vector_type(8)));
typedef float f32x4 __attribute__((ext_vector_type(4)));

__device__ __forceinline__ void gload16(const void* g, void* l) {
  __builtin_amdgcn_global_load_lds(
      (const __attribute__((address_space(1))) void*)g,
      (__attribute__((address_space(3))) void*)l, 16, 0, 0);
}

// ---------------- kNN: one WAVE per query point, barrier-free selection ----------------
__global__ __launch_bounds__(256) void knn_kernel(const float* __restrict__ pos,
                                                  int* __restrict__ nbr) {
  __shared__ float px[1024], py[1024], pz[1024], sq[1024];
  int tid = threadIdx.x;
  int b = blockIdx.x >> 8;                 // graph id (256 blocks per graph)
  const float* pg = pos + (size_t)b * 3072;
  for (int m = 0; m < 4; ++m) {
    int j = m * 256 + tid;
    float x = pg[3 * j], y = pg[3 * j + 1], z = pg[3 * j + 2];
    px[j] = x; py[j] = y; pz[j] = z; sq[j] = x * x + y * y + z * z;
  }
  __syncthreads();
  int wave = tid >> 6, lane = tid & 63;
  int n = (blockIdx.x & 255) * 4 + wave;   // local query index in graph
  float xi = px[n], yi = py[n], zi = pz[n], si = sq[n];
  float d[16];
#pragma unroll
  for (int i = 0; i < 16; ++i) {
    int j = i * 64 + lane;
    float dd = si + sq[j] - 2.0f * (xi * px[j] + yi * py[j] + zi * pz[j]);
    d[i] = (j == n) ? 1e30f : dd;          // exclude self
  }
  int outbase = (b * 1024 + n) * 20;
  for (int kk = 0; kk < 20; ++kk) {
    float lmin = d[0]; int lpos = 0;
#pragma unroll
    for (int i = 1; i < 16; ++i)
      if (d[i] < lmin) { lmin = d[i]; lpos = i; }
    float bv = lmin; int bi = lpos * 64 + lane;
#pragma unroll
    for (int off = 1; off < 64; off <<= 1) {
      float ov = __shfl_xor(bv, off);
      int   oi = __shfl_xor(bi, off);
      if (ov < bv || (ov == bv && oi < bi)) { bv = ov; bi = oi; }
    }
    if (lane == 0) nbr[outbase + kk] = b * 1024 + bi;
    if ((bi & 63) == lane) {
      int rp = bi >> 6;
#pragma unroll
      for (int i = 0; i < 16; ++i)
        if (i == rp) d[i] = 1e30f;
    }
  }
}

// ---------------- edge MLP layer1 stats (sum, sumsq per channel) ----------------
__global__ __launch_bounds__(256) void edge_stats_kernel(
    const float* __restrict__ pos, const int* __restrict__ nbr,
    const float* __restrict__ W1, const float* __restrict__ b1v,
    float* __restrict__ psum, float* __restrict__ psq) {
  __shared__ float els[256][6];
  __shared__ float w1s[384];
  __shared__ float b1s[64];
  __shared__ float red[8][64];
  int tid = threadIdx.x, bid = blockIdx.x;
  for (int f = tid; f < 384; f += 256) w1s[f] = W1[f];
  if (tid < 64) b1s[tid] = b1v[tid];
  int c = tid & 63, grp = tid >> 6;
  float s = 0.f, s2 = 0.f;
  for (int ch = 0; ch < 5; ++ch) {
    int E = bid * 1280 + ch * 256 + tid;
    int p = E / 20;
    int j = nbr[E];
    float pix = pos[3 * p], piy = pos[3 * p + 1], piz = pos[3 * p + 2];
    float e3 = pos[3 * j] - pix, e4 = pos[3 * j + 1] - piy, e5 = pos[3 * j + 2] - piz;
    __syncthreads();
    els[tid][0] = pix; els[tid][1] = piy; els[tid][2] = piz;
    els[tid][3] = e3;  els[tid][4] = e4;  els[tid][5] = e5;
    __syncthreads();
    for (int m = 0; m < 64; ++m) {
      int e = grp * 64 + m;
      float h = b1s[c];
#pragma unroll
      for (int d = 0; d < 6; ++d) h += els[e][d] * w1s[d * 64 + c];
      s += h; s2 += h * h;
    }
  }
  red[grp][c] = s;
  __syncthreads();
  red[4 + grp][c] = s2;
  __syncthreads();
  if (tid < 64) {
    float S = red[0][tid] + red[1][tid] + red[2][tid] + red[3][tid];
    float Q = red[4][tid] + red[5][tid] + red[6][tid] + red[7][tid];
    psum[bid * 64 + tid] = S;
    psq[bid * 64 + tid] = Q;
  }
}

__global__ void bn_finalize_kernel(const float* __restrict__ psum, const float* __restrict__ psq,
                                   const float* __restrict__ gamma, const float* __restrict__ beta,
                                   float* __restrict__ bns, float* __restrict__ bnh) {
  int c = threadIdx.x;   // 64 threads
  float s = 0.f, q = 0.f;
  for (int b = 0; b < 512; ++b) { s += psum[b * 64 + c]; q += psq[b * 64 + c]; }
  const float inv = 1.0f / 655360.0f;
  float mu = s * inv;
  float var = q * inv - mu * mu;
  float sc = gamma[c] * rsqrtf(var + 1e-5f);
  bns[c] = sc;
  bnh[c] = beta[c] - mu * sc;
}

// ---------------- edge MLP via split-f16 MFMA (fp32-accurate) ----------------
__global__ __launch_bounds__(256) void edge_mlp_kernel(
    const float* __restrict__ pos, const int* __restrict__ nbr,
    const float* __restrict__ W1, const float* __restrict__ b1v,
    const float* __restrict__ bns, const float* __restrict__ bnh,
    const float* __restrict__ W2, const float* __restrict__ b2v,
    float* __restrict__ x1) {
  __shared__ __align__(16) char elds[53248];
  _Float16* Ah = (_Float16*)(elds);            // [80][64] swizzled, 10240 B
  _Float16* Al = (_Float16*)(elds + 10240);    // 10240 B
  _Float16* Bh = (_Float16*)(elds + 20480);    // [128 cols][64] swizzled, 16384 B
  _Float16* Bl = (_Float16*)(elds + 36864);    // 16384 B
  float* outb = (float*)elds;                  // [80][129] fp32, reused after MFMA
  __shared__ float w1s[384];
  __shared__ float b1s[64], scs[64], shs[64];
  int tid = threadIdx.x, bid = blockIdx.x;
  for (int f = tid; f < 384; f += 256) w1s[f] = W1[f];
  if (tid < 64) { b1s[tid] = b1v[tid]; scs[tid] = bns[tid]; shs[tid] = bnh[tid]; }
#pragma unroll
  for (int i = 0; i < 32; ++i) {
    int flat = tid + 256 * i;        // d = flat>>7 (0..63), c = flat&127
    int dd = flat >> 7, c = flat & 127;
    float v = W2[flat];
    _Float16 hi = (_Float16)v;
    _Float16 lo = (_Float16)(v - (float)hi);
    int byte = c * 128 + ((((dd >> 3) ^ (c & 7))) << 4) + (dd & 7) * 2;
    *(_Float16*)((char*)Bh + byte) = hi;
    *(_Float16*)((char*)Bl + byte) = lo;
  }
  __syncthreads();
#pragma unroll
  for (int m = 0; m < 20; ++m) {
    int flat = tid + 256 * m;
    int row = flat >> 6;            // 0..79
    int d = flat & 63;
    int j = nbr[bid * 80 + row];
    int P = bid * 4 + (row / 20);
    float pix = pos[3 * P], piy = pos[3 * P + 1], piz = pos[3 * P + 2];
    float e3 = pos[3 * j] - pix, e4 = pos[3 * j + 1] - piy, e5 = pos[3 * j + 2] - piz;
    float h = b1s[d];
    h += pix * w1s[d] + piy * w1s[64 + d] + piz * w1s[128 + d]
       + e3 * w1s[192 + d] + e4 * w1s[256 + d] + e5 * w1s[320 + d];
    h = scs[d] * h + shs[d];
    h = fmaxf(h, 0.f);
    _Float16 hi = (_Float16)h;
    _Float16 lo = (_Float16)(h - (float)hi);
    int byte = row * 128 + ((((d >> 3) ^ (row & 7))) << 4) + (d & 7) * 2;
    *(_Float16*)((char*)Ah + byte) = hi;
    *(_Float16*)((char*)Al + byte) = lo;
  }
  __syncthreads();
  int wave = tid >> 6, lane = tid & 63;
  int l15 = lane & 15, l4 = lane >> 4;
  f32x4 acc[5][2] = {};
#pragma unroll
  for (int ks = 0; ks < 2; ++ks) {
    int slotk = ks * 4 + l4;
    half8 bfh[2], bfl[2];
#pragma unroll
    for (int ci = 0; ci < 2; ++ci) {
      int col = (wave * 2 + ci) * 16 + l15;
      int byte = col * 128 + ((slotk ^ (col & 7)) << 4);
      bfh[ci] = *(const half8*)((char*)Bh + byte);
      bfl[ci] = *(const half8*)((char*)Bl + byte);
    }
#pragma unroll
    for (int rt = 0; rt < 5; ++rt) {
      int row = rt * 16 + l15;
      int byte = row * 128 + ((slotk ^ (row & 7)) << 4);
      half8 ah = *(const half8*)((char*)Ah + byte);
      half8 al = *(const half8*)((char*)Al + byte);
#pragma unroll
      for (int ci = 0; ci < 2; ++ci) {
        acc[rt][ci] = __builtin_amdgcn_mfma_f32_16x16x32_f16(ah, bfh[ci], acc[rt][ci], 0, 0, 0);
        acc[rt][ci] = __builtin_amdgcn_mfma_f32_16x16x32_f16(ah, bfl[ci], acc[rt][ci], 0, 0, 0);
        acc[rt][ci] = __builtin_amdgcn_mfma_f32_16x16x32_f16(al, bfh[ci], acc[rt][ci], 0, 0, 0);
      }
    }
  }
  __syncthreads();   // A/B reads done -> outb may overwrite
#pragma unroll
  for (int rt = 0; rt < 5; ++rt)
#pragma unroll
    for (int ci = 0; ci < 2; ++ci) {
      int col = (wave * 2 + ci) * 16 + l15;
#pragma unroll
      for (int q = 0; q < 4; ++q) {
        int row = rt * 16 + l4 * 4 + q;
        outb[row * 129 + col] = acc[rt][ci][q];
      }
    }
  __syncthreads();
#pragma unroll
  for (int r = 0; r < 2; ++r) {
    int it = tid + 256 * r;          // 512 items: p = it>>7, c = it&127
    int p = it >> 7, c = it & 127;
    float mx = -1e30f;
#pragma unroll
    for (int e = 0; e < 20; ++e) mx = fmaxf(mx, outb[(p * 20 + e) * 129 + c]);
    x1[((size_t)bid * 4 + p) * 128 + c] = mx + b2v[c];
  }
}

// ---------------- c1 [2,1024,4,52,7] -> Cf16 [1024][3328], reordered k-axis ----------------
// k = w*64 + (phase*4 + n)*8 + (g-1); slot e==7 zero-padded.
__global__ void c1_to_f16_kernel(const float* __restrict__ c1, _Float16* __restrict__ Cf) {
  int L = blockIdx.x * 256 + threadIdx.x;
  if (L >= 1024 * 3328) return;
  int o = L / 3328, rem = L % 3328;
  int w = rem >> 6, idx = rem & 63;
  int s = idx >> 3, e = idx & 7;
  int phase = s >> 2, n = s & 3;
  float v = 0.0f;
  if (e < 7)
    v = c1[((((size_t)phase * 1024 + o) * 4 + n) * 52 + w) * 7 + e];
  Cf[L] = (_Float16)v;
}

// ---------------- KAN1 MFMA GEMM [32768,3328]x[3328,1024] ----------------
// BM=128 BN=256 BK=64, 512 thr (8 waves 2x4), wave tile 64x64.
// x1 tile in LDS (no global gathers in the K-loop); A-gen = Chebyshev recurrence
// (1 sincos + 6 FMA per 8 elements). 2-phase double-buffered pipeline.
__global__ __launch_bounds__(512, 2) void kan1_gemm_kernel(
    const float* __restrict__ x1, const _Float16* __restrict__ Cf,
    float* __restrict__ pmax, float* __restrict__ psump) {
  __shared__ __align__(16) float xs[128 * 112];        // 57344 B (dims 0..111 used)
  __shared__ __align__(16) _Float16 Asm[2][128 * 64];  // 32768 B, swizzled
  __shared__ __align__(16) _Float16 Bsm[2][256 * 64];  // 65536 B, swizzled
  int tid = threadIdx.x;
  int bm = blockIdx.x, bn = blockIdx.y;
  int m0 = bm << 7, n0 = bn << 8;
  int wave = tid >> 6, lane = tid & 63;
  int wr = wave >> 2, wc = wave & 3;        // 2 x 4 wave grid
  int l15 = lane & 15, l4 = lane >> 4;

  auto stageB = [&](int t, int nb) {
    int j0 = t << 6;
#pragma unroll
    for (int i = 0; i < 4; ++i) {
      int idx = i * 512 + tid;          // 0..2047 : col = idx>>3, slot = idx&7
      int col = idx >> 3, slot = idx & 7;
      int sslot = slot ^ (col & 7);
      gload16(Cf + (size_t)(n0 + col) * 3328 + j0 + sslot * 8,
              (char*)Bsm[nb] + idx * 16);
    }
  };
  // chunk t == tap w; thread handles slot s = (phase*4+n), rows (tid>>3) and (tid>>3)+64
  int sA = tid & 7;
  int phA = sA >> 2, nA = sA & 3;
  auto agen = [&](int t, int nb) {
    float bart = 1.0f - fabsf((float)(2 * t) * (1.0f / 52.0f) - 1.0f);
    int d = nA * 20 + t;
#pragma unroll
    for (int rep = 0; rep < 2; ++rep) {
      int r = (tid >> 3) + rep * 64;
      float th = xs[r * 112 + d] * bart;
      float sn, cs;
      __sincosf(th, &sn, &cs);
      float c2 = 2.0f * cs;
      float p0 = phA ? sn : cs;
      float p1 = phA ? c2 * sn : c2 * cs - 1.0f;
      half8 av;
      av[0] = (_Float16)p0; av[1] = (_Float16)p1;
      float pm2 = p0, pm1 = p1;
#pragma unroll
      for (int g = 2; g < 7; ++g) {
        float pg = c2 * pm1 - pm2;
        av[g] = (_Float16)pg;
        pm2 = pm1; pm1 = pg;
      }
      av[7] = (_Float16)0.0f;
      *(half8*)((char*)Asm[nb] + r * 128 + ((sA ^ (r & 7)) << 4)) = av;
    }
  };

  // ---- prologue: stage x tile (128 rows x 112 f32) + B chunk 0; then A chunk 0 ----
#pragma unroll
  for (int i = 0; i < 7; ++i) {
    int idx = i * 512 + tid;          // 0..3583, 16B each
    int f = idx * 4;
    int row = f / 112, col = f - row * 112;
    gload16(x1 + (size_t)(m0 + row) * 128 + col, (char*)xs + idx * 16);
  }
  stageB(0, 0);
  f32x4 acc[4][4] = {};
  __syncthreads();                    // drains vmcnt: xs + Bsm[0] ready
  agen(0, 0);
  __syncthreads();                    // Asm[0] visible

  for (int t = 0; t < 52; ++t) {
    int cur = t & 1, nxt = cur ^ 1;
    if (t < 51) stageB(t + 1, nxt);   // prefetch B (drained at end-of-iter barrier)
    // MFMA operands -> regs
    half8 af[2][4], bf[2][4];
#pragma unroll
    for (int ksub = 0; ksub < 2; ++ksub) {
      int slotk = ksub * 4 + l4;
#pragma unroll
      for (int mi = 0; mi < 4; ++mi) {
        int row = wr * 64 + mi * 16 + l15;
        af[ksub][mi] = *(const half8*)((char*)Asm[cur] + row * 128 + ((slotk ^ (row & 7)) << 4));
      }
#pragma unroll
      for (int ni = 0; ni < 4; ++ni) {
        int col = wc * 64 + ni * 16 + l15;
        bf[ksub][ni] = *(const half8*)((char*)Bsm[cur] + col * 128 + ((slotk ^ (col & 7)) << 4));
      }
    }
    if (t < 51) agen(t + 1, nxt);     // VALU trig for next tile (LDS-only deps)
    // register-only MFMAs overlap the trig above
#pragma unroll
    for (int ksub = 0; ksub < 2; ++ksub)
#pragma unroll
      for (int mi = 0; mi < 4; ++mi)
#pragma unroll
        for (int ni = 0; ni < 4; ++ni)
          acc[mi][ni] = __builtin_amdgcn_mfma_f32_16x16x32_f16(af[ksub][mi], bf[ksub][ni], acc[mi][ni], 0, 0, 0);
    __syncthreads();
  }

  // ---- fused pooling epilogue: max/sum over the block's 128 rows ----
  float* pooled = (float*)xs;           // [wr][max|sum][256], 4 KB
#pragma unroll
  for (int ni = 0; ni < 4; ++ni) {
    float mx = -1e30f, sm = 0.f;
#pragma unroll
    for (int mi = 0; mi < 4; ++mi)
#pragma unroll
      for (int q = 0; q < 4; ++q) {
        float v = acc[mi][ni][q];
        mx = fmaxf(mx, v); sm += v;
      }
    mx = fmaxf(mx, __shfl_xor(mx, 16)); sm += __shfl_xor(sm, 16);
    mx = fmaxf(mx, __shfl_xor(mx, 32)); sm += __shfl_xor(sm, 32);
    if (l4 == 0) {
      int col = wc * 64 + ni * 16 + l15;
      pooled[(wr * 2 + 0) * 256 + col] = mx;
      pooled[(wr * 2 + 1) * 256 + col] = sm;
    }
  }
  __syncthreads();
  if (tid < 256) {
    float mx = fmaxf(pooled[tid], pooled[512 + tid]);
    float sm = pooled[256 + tid] + pooled[768 + tid];
    pmax[(size_t)bm * 1024 + n0 + tid] = mx;
    psump[(size_t)bm * 1024 + n0 + tid] = sm;
  }
}

// ---------------- final pool: 8 m-block partials -> gmax/gmean (+bi1) ----------------
__global__ void pool_reduce_kernel(const float* __restrict__ pmax, const float* __restrict__ psump,
                                   const float* __restrict__ bi1,
                                   float* __restrict__ gmax, float* __restrict__ gmean) {
  int gid = blockIdx.x * 256 + threadIdx.x;   // 32768 = 32 graphs x 1024 cols
  int b = gid >> 10, col = gid & 1023;
  float mx = -1e30f, sm = 0.f;
  for (int t = 0; t < 8; ++t) {
    mx = fmaxf(mx, pmax[(size_t)(b * 8 + t) * 1024 + col]);
    sm += psump[(size_t)(b * 8 + t) * 1024 + col];
  }
  float bias = bi1[col];
  gmax[gid] = mx + bias;
  gmean[gid] = sm * (1.0f / 1024.0f) + bias;
}

// ---------------- STFT-KAN2 partials: xcat [32,2048] -> part [32,16,7] ----------------
__global__ __launch_bounds__(256) void kan2_kernel(
    const float* __restrict__ gmax, const float* __restrict__ gmean,
    const float* __restrict__ c2, float* __restrict__ part) {
  __shared__ float xc[2048];
  __shared__ float hw[197];
  __shared__ float racc[7][256];
  int b = blockIdx.x, s = blockIdx.y, tid = threadIdx.x;
  for (int f = tid; f < 1024; f += 256) {
    xc[f] = gmax[b * 1024 + f];
    xc[1024 + f] = gmean[b * 1024 + f];
  }
  for (int f = tid; f < 197; f += 256)
    hw[f] = 0.5f * (1.0f - cosf(6.283185307179586f * (float)f / 197.0f));
  float acc[7] = {};
  __syncthreads();
  int qlo = (52205 * s) / 16, qhi = (52205 * (s + 1)) / 16;
  for (int q = qlo + tid; q < qhi; q += 256) {
    int n = q / 197;
    int w = q - n * 197;
    float xw = xc[n * 7 + w] * hw[w];
    float s1, c1v;
    __sincosf(xw, &s1, &c1v);
    float ckv[6], skv[6];
    {
      float ck = c1v, sk = s1;
#pragma unroll
      for (int g = 0; g < 6; ++g) {
        ckv[g] = ck; skv[g] = sk;
        float cn = ck * c1v - sk * s1;
        sk = sk * c1v + ck * s1;
        ck = cn;
      }
    }
    int base = q * 6;
#pragma unroll
    for (int o = 0; o < 7; ++o) {
      const float* pc = c2 + (size_t)o * 313230 + base;
      const float* ps = c2 + (size_t)(o + 7) * 313230 + base;
      float sc = 0.f, ss = 0.f;
#pragma unroll
      for (int g = 0; g < 6; ++g) { sc += ckv[g] * pc[g]; ss += skv[g] * ps[g]; }
      acc[o] += sc + ss;
    }
  }
#pragma unroll
  for (int o = 0; o < 7; ++o) racc[o][tid] = acc[o];
  __syncthreads();
  for (int st = 128; st >= 1; st >>= 1) {
    if (tid < st)
#pragma unroll
      for (int o = 0; o < 7; ++o) racc[o][tid] += racc[o][tid + st];
    __syncthreads();
  }
  if (tid < 7) part[(b * 16 + s) * 7 + tid] = racc[tid][0];
}

__global__ void kan2_reduce_kernel(const float* __restrict__ part, const float* __restrict__ bi2,
                                   float* __restrict__ out) {
  int i = threadIdx.x;   // 224 threads: (b, o)
  if (i >= 224) return;
  int b = i / 7, o = i % 7;
  float s = 0.f;
  for (int t = 0; t < 16; ++t) s += part[(b * 16 + t) * 7 + o];
  out[b * 7 + o] = s + bi2[o];
}

// ---------------------------------------------------------------------------
extern "C" void kernel_launch(void* const* d_in, const int* in_sizes, int n_in,
                              void* d_out, int out_size, void* d_ws, size_t ws_size,
                              hipStream_t stream) {
  const float* pos    = (const float*)d_in[0];
  const float* W1     = (const float*)d_in[2];
  const float* b1     = (const float*)d_in[3];
  const float* gamma1 = (const float*)d_in[4];
  const float* beta1  = (const float*)d_in[5];
  const float* W2     = (const float*)d_in[6];
  const float* b2     = (const float*)d_in[7];
  const float* c1     = (const float*)d_in[8];
  const float* bi1    = (const float*)d_in[9];
  const float* c2     = (const float*)d_in[10];
  const float* bi2    = (const float*)d_in[11];
  float* out = (float*)d_out;
  char* ws = (char*)d_ws;

  int*      nbr   = (int*)     (ws + 0);          // 2,621,440
  float*    x1    = (float*)   (ws + 2621440);    // 16,777,216
  _Float16* Cf    = (_Float16*)(ws + 19398656);   // 1024*3328*2 = 6,815,744
  float*    psum  = (float*)   (ws + 26214400);   // 131,072
  float*    psq   = (float*)   (ws + 26345472);   // 131,072
  float*    bns   = (float*)   (ws + 26476544);   // 256
  float*    bnh   = (float*)   (ws + 26476800);   // 256
  float*    pmax  = (float*)   (ws + 26477056);   // 1,048,576
  float*    psump = (float*)   (ws + 27525632);   // 1,048,576
  float*    gmax  = (float*)   (ws + 28574208);   // 131,072
  float*    gmean = (float*)   (ws + 28705280);   // 131,072
  float*    part  = (float*)   (ws + 28836352);   // 14,336
  if (ws_size < 28850688) return;

  knn_kernel<<<8192, 256, 0, stream>>>(pos, nbr);
  c1_to_f16_kernel<<<13312, 256, 0, stream>>>(c1, Cf);
  edge_stats_kernel<<<512, 256, 0, stream>>>(pos, nbr, W1, b1, psum, psq);
  bn_finalize_kernel<<<1, 64, 0, stream>>>(psum, psq, gamma1, beta1, bns, bnh);
  edge_mlp_kernel<<<8192, 256, 0, stream>>>(pos, nbr, W1, b1, bns, bnh, W2, b2, x1);
  kan1_gemm_kernel<<<dim3(256, 4), 512, 0, stream>>>(x1, Cf, pmax, psump);
  pool_reduce_kernel<<<128, 256, 0, stream>>>(pmax, psump, bi1, gmax, gmean);
  kan2_kernel<<<dim3(32, 16), 256, 0, stream>>>(gmax, gmean, c2, part);
  kan2_reduce_kernel<<<1, 256, 0, stream>>>(part, bi2, out);
}